// Round 4
// baseline (764.051 us; speedup 1.0000x reference)
//
#include <hip/hip_runtime.h>
#include <hip/hip_fp16.h>

#define BB   2
#define NN   50000
#define EE   800000
#define INCH 64
#define C1   16
#define C2   32
#define NB   (BB*NN)

// radix binning geometry
#define W1S   6                      // layer-1 bucket = 64 dst nodes
#define W2S   5                      // layer-2 bucket = 32 dst nodes
#define NBK1  ((NN + 63) >> 6)       // 782
#define NBK2  ((NN + 31) >> 5)       // 1563
#define NBKT  (NBK1 + NBK2)          // 2345
#define EB    16384                  // edges per binning block
#define NEBLK ((2*EE + EB - 1) / EB) // 98

// workspace layout (float-unit offsets)
#define OFF_XS1   0                          // NB*C1 halves
#define OFF_XS2   (OFF_XS1 + NB*C1/2)        // NB*C2 halves
#define OFF_DOTK1 (OFF_XS2 + NB*C2/2)
#define OFF_DOTQ1 (OFF_DOTK1 + NB)
#define OFF_DOTK2 (OFF_DOTQ1 + NB)
#define OFF_DOTQ2 (OFF_DOTK2 + NB)
#define OFF_AG1   (OFF_DOTQ2 + NB)           // NN*32 floats
#define OFF_AG2   (OFF_AG1 + NN*32)          // NN*64 floats
#define OFF_BCNT  (OFF_AG2 + NN*64)          // NEBLK*NBKT u32 (in-place -> offsets)
#define OFF_BTOT  (OFF_BCNT + NEBLK*NBKT)    // NBKT u32
#define OFF_BBASE (OFF_BTOT + NBKT)          // NBKT u32
#define OFF_RECS  (OFF_BBASE + NBKT)         // 2*EE uint2
#define OFF_SC    (OFF_RECS + 2*EE*2)

__device__ __forceinline__ float sigmoidf(float x) {
    return 1.0f / (1.0f + __expf(-x));
}

// native ds_add_f32 (NOT a CAS loop like plain atomicAdd(float*))
__device__ __forceinline__ void ldsAddF(float* p, float v) {
    unsafeAtomicAdd(p, v);
}

// ---------------- tiny scalar precompute -------------------------------------
__global__ void k_sc(const float* __restrict__ we1, const float* __restrict__ aw1,
                     const float* __restrict__ we2, const float* __restrict__ aw2,
                     float* __restrict__ sc) {
    if (threadIdx.x == 0) {
        float e = 0.f;
        for (int j = 0; j < C1; ++j) e += we1[j] * aw1[2*C1+j];
        sc[0] = e;
    }
    if (threadIdx.x == 1) {
        float e = 0.f;
        for (int j = 0; j < C2; ++j) e += we2[j] * aw2[2*C2+j];
        sc[1] = e;
    }
}

// ---------------- pass A: per-(block,bucket) histogram -----------------------
__global__ __launch_bounds__(256) void k_cnt(
        const int* __restrict__ ei0, const int* __restrict__ ei1,
        unsigned* __restrict__ blockCnt) {
    __shared__ unsigned h[NBKT];
    int tid = threadIdx.x;
    for (int i = tid; i < NBKT; i += 256) h[i] = 0u;
    __syncthreads();
    int base = blockIdx.x * EB;
#pragma unroll 4
    for (int j = 0; j < EB/256; ++j) {
        int t = base + j*256 + tid;
        if (t < 2*EE) {
            int bkt;
            if (t < EE) { int dst = ei0[EE + t];      bkt = dst >> W1S; }
            else        { int dst = ei1[EE + t - EE]; bkt = NBK1 + (dst >> W2S); }
            atomicAdd(&h[bkt], 1u);
        }
    }
    __syncthreads();
    unsigned* o = blockCnt + (size_t)blockIdx.x * NBKT;
    for (int i = tid; i < NBKT; i += 256) o[i] = h[i];
}

// ---------------- pass B1: scan over blocks, per bucket (in-place) -----------
__global__ __launch_bounds__(128) void k_scanBkt(
        unsigned* __restrict__ blockCnt, unsigned* __restrict__ bktTot) {
    __shared__ unsigned s[128];
    int tid = threadIdx.x;
    int bkt = blockIdx.x;
    unsigned v = (tid < NEBLK) ? blockCnt[(size_t)tid * NBKT + bkt] : 0u;
    s[tid] = v;
    __syncthreads();
    for (int o = 1; o < 128; o <<= 1) {
        unsigned t = (tid >= o) ? s[tid - o] : 0u;
        __syncthreads();
        s[tid] += t;
        __syncthreads();
    }
    if (tid < NEBLK) blockCnt[(size_t)tid * NBKT + bkt] = s[tid] - v;  // exclusive
    if (tid == 127) bktTot[bkt] = s[127];
}

// ---------------- pass B2: scan bucket totals -> bucket bases ----------------
__global__ __launch_bounds__(1024) void k_scanTot(
        const unsigned* __restrict__ bktTot, unsigned* __restrict__ bucketBase) {
    __shared__ unsigned s[1024];
    int tid = threadIdx.x;
    int base = tid * 3;
    unsigned a0 = (base + 0 < NBKT) ? bktTot[base + 0] : 0u;
    unsigned a1 = (base + 1 < NBKT) ? bktTot[base + 1] : 0u;
    unsigned a2 = (base + 2 < NBKT) ? bktTot[base + 2] : 0u;
    unsigned l = a0 + a1 + a2;
    s[tid] = l;
    __syncthreads();
    for (int o = 1; o < 1024; o <<= 1) {
        unsigned t = (tid >= o) ? s[tid - o] : 0u;
        __syncthreads();
        s[tid] += t;
        __syncthreads();
    }
    unsigned ex = s[tid] - l;
    if (base + 0 < NBKT) bucketBase[base + 0] = ex;
    if (base + 1 < NBKT) bucketBase[base + 1] = ex + a0;
    if (base + 2 < NBKT) bucketBase[base + 2] = ex + a0 + a1;
}

// ---------------- pass C: permute edge records into bucket-grouped order -----
__global__ __launch_bounds__(256) void k_permute(
        const int* __restrict__ ei0, const int* __restrict__ ei1,
        const float* __restrict__ ew0, const float* __restrict__ ew1,
        const unsigned* __restrict__ blockOff, const unsigned* __restrict__ bucketBase,
        uint2* __restrict__ recs) {
    __shared__ unsigned off[NBKT];
    __shared__ unsigned cur[NBKT];
    int tid = threadIdx.x;
    const unsigned* bo = blockOff + (size_t)blockIdx.x * NBKT;
    for (int i = tid; i < NBKT; i += 256) { off[i] = bo[i] + bucketBase[i]; cur[i] = 0u; }
    __syncthreads();
    int base = blockIdx.x * EB;
    for (int j = 0; j < EB/256; ++j) {
        int t = base + j*256 + tid;
        if (t >= 2*EE) break;
        int bkt, dl, src; float ef;
        if (t < EE) {
            int dst = ei0[EE + t];
            bkt = dst >> W1S; dl = dst & 63;
            src = ei0[t]; ef = ew0[t];
        } else {
            int e = t - EE;
            int dst = ei1[EE + e];
            bkt = NBK1 + (dst >> W2S); dl = dst & 31;
            src = ei1[e]; ef = ew1[e];
        }
        unsigned pos = off[bkt] + atomicAdd(&cur[bkt], 1u);
        recs[pos] = make_uint2((unsigned)src | ((unsigned)dl << 16), __float_as_uint(ef));
    }
}

// ---------------- layer 1: xs1 = X @ value1 (half-packed out) ----------------
__global__ __launch_bounds__(256) void k_value1(
        const float* __restrict__ X, const float* __restrict__ value1,
        const float* __restrict__ key1, const float* __restrict__ query1,
        const float* __restrict__ aw1,
        __half* __restrict__ xs1h, float* __restrict__ dotk1, float* __restrict__ dotq1) {
    __shared__ float W[INCH*C1];
    __shared__ float KV[C1], QV[C1];
    int tid = threadIdx.x;
    for (int i = tid; i < INCH*C1; i += 256) W[i] = value1[i];
    if (tid < C1) {
        float kv = 0.f, qv = 0.f;
#pragma unroll
        for (int j = 0; j < C1; ++j) {
            kv += key1[tid*C1+j]   * aw1[j];
            qv += query1[tid*C1+j] * aw1[C1+j];
        }
        KV[tid] = kv; QV[tid] = qv;
    }
    __syncthreads();
    int bn = blockIdx.x * 256 + tid;
    if (bn >= NB) return;
    int b = (bn >= NN) ? 1 : 0;
    int node = bn - b*NN;
    const float4* Xr = (const float4*)(X + (size_t)bn * INCH);
    float acc[C1];
#pragma unroll
    for (int j = 0; j < C1; ++j) acc[j] = 0.f;
#pragma unroll
    for (int v = 0; v < 16; ++v) {
        float4 p = Xr[v];
        float x4[4] = {p.x, p.y, p.z, p.w};
#pragma unroll
        for (int h = 0; h < 4; ++h) {
            int i = v*4 + h;
            float xv = x4[h];
#pragma unroll
            for (int j = 0; j < C1; ++j) acc[j] += xv * W[i*C1+j];
        }
    }
    float dk = 0.f, dq = 0.f;
#pragma unroll
    for (int j = 0; j < C1; ++j) { dk += acc[j]*KV[j]; dq += acc[j]*QV[j]; }
    __half* o = xs1h + ((size_t)node * C1) * 2 + b;
#pragma unroll
    for (int j = 0; j < C1; ++j) o[2*j] = __float2half_rn(acc[j]);
    dotk1[node*2 + b] = dk; dotq1[node*2 + b] = dq;
}

// ---------------- layer-1 bucket aggregation (LDS accumulators) --------------
// block = one bucket of 64 dst nodes; 8 lanes per record (cp = channel pair)
// stride 33: bank = (dl + 4cp + j) mod 32 -> full 32-bank spread
#define A1STRIDE 33
__global__ __launch_bounds__(256) void k_baggr1(
        const float* __restrict__ we, const float* __restrict__ ab,
        const float* __restrict__ sc,
        const uint2* __restrict__ xsh, const float* __restrict__ dotk,
        const float* __restrict__ dotq,
        const uint2* __restrict__ recs, const unsigned* __restrict__ bktTot,
        const unsigned* __restrict__ bucketBase, float* __restrict__ aggrf) {
    __shared__ float A[64 * A1STRIDE];
    __shared__ float DK[64 * 2];
    int tid = threadIdx.x;
    int bkt = blockIdx.x;
    int nb0 = bkt << W1S;
    for (int i = tid; i < 64 * A1STRIDE; i += 256) A[i] = 0.f;
    for (int i = tid; i < 128; i += 256)
        DK[i] = (nb0*2 + i < 2*NN) ? dotk[nb0*2 + i] : 0.f;
    __syncthreads();
    unsigned cnt  = bktTot[bkt];
    unsigned base = bucketBase[bkt];
    int cp = tid & 7;
    float w0 = we[2*cp], w1 = we[2*cp+1];
    float ec = sc[0], bias = ab[0];
    unsigned i = tid >> 3;
    uint2 r = (i < cnt) ? recs[base + i] : make_uint2(0u, 0u);
    for (; i < cnt; i += 32) {
        uint2 rc = r;
        if (i + 32 < cnt) r = recs[base + i + 32];
        int src = rc.x & 0xffff;
        int dl  = rc.x >> 16;
        float ef = __uint_as_float(rc.y);
        float se0 = sigmoidf(ef * w0);
        float se1 = sigmoidf(ef * w1);
        float eb  = ef * ec + bias;
        float2 dq = *(const float2*)(dotq + src*2);
        float a0 = sigmoidf(DK[dl*2]   + dq.x + eb);
        float a1 = sigmoidf(DK[dl*2+1] + dq.y + eb);
        uint2 xr = xsh[(size_t)src*8 + cp];
        float2 f0 = __half22float2(__builtin_bit_cast(__half2, xr.x));
        float2 f1 = __half22float2(__builtin_bit_cast(__half2, xr.y));
        float* a = &A[dl*A1STRIDE + cp*4];
        ldsAddF(a + 0, a0 * se0 * f0.x);
        ldsAddF(a + 1, a1 * se0 * f0.y);
        ldsAddF(a + 2, a0 * se1 * f1.x);
        ldsAddF(a + 3, a1 * se1 * f1.y);
    }
    __syncthreads();
    for (int i2 = tid; i2 < 64*32; i2 += 256) {
        int node = nb0 + (i2 >> 5);
        if (node < NN) aggrf[(size_t)node*32 + (i2 & 31)] = A[(i2 >> 5)*A1STRIDE + (i2 & 31)];
    }
}

// ---------------- fused: update1 + leaky_relu + xs2 = X1 @ value2 ------------
__global__ __launch_bounds__(256) void k_update1(
        const float* __restrict__ cat_w, const float* __restrict__ cat_b,
        const float* __restrict__ value2,
        const float* __restrict__ key2, const float* __restrict__ query2,
        const float* __restrict__ aw2,
        const __half* __restrict__ xs1h, const float* __restrict__ aggr1f,
        __half* __restrict__ xs2h, float* __restrict__ dotk2, float* __restrict__ dotq2) {
    __shared__ float CW[2*C1*C1];
    __shared__ float CB[C1];
    __shared__ float V2[C1*C2];
    __shared__ float KV[C2], QV[C2];
    int tid = threadIdx.x;
    for (int i = tid; i < 2*C1*C1; i += 256) CW[i] = cat_w[i];
    for (int i = tid; i < C1*C2;   i += 256) V2[i] = value2[i];
    if (tid < C1) CB[tid] = cat_b[tid];
    if (tid < C2) {
        float kv = 0.f;
#pragma unroll
        for (int j = 0; j < C2; ++j) kv += key2[tid*C2+j] * aw2[j];
        KV[tid] = kv;
    } else if (tid < 2*C2) {
        int c = tid - C2;
        float qv = 0.f;
#pragma unroll
        for (int j = 0; j < C2; ++j) qv += query2[c*C2+j] * aw2[C2+j];
        QV[c] = qv;
    }
    __syncthreads();
    int bn = blockIdx.x * 256 + tid;
    if (bn >= NB) return;
    int b = (bn >= NN) ? 1 : 0;
    int node = bn - b*NN;
    const __half* xr = xs1h + ((size_t)node*C1)*2 + b;
    const float* agp = aggr1f + (size_t)node*32;
    float xd[C1], ag[C1];
#pragma unroll
    for (int i = 0; i < C1; ++i) xd[i] = __half2float(xr[2*i]);
#pragma unroll
    for (int i = 0; i < C1; ++i) ag[i] = agp[(i>>1)*4 + (i&1)*2 + b];
    float x1[C1];
#pragma unroll
    for (int j = 0; j < C1; ++j) {
        float u = CB[j];
#pragma unroll
        for (int i = 0; i < C1; ++i) {
            u += xd[i] * CW[i*C1 + j];
            u += ag[i] * CW[(C1+i)*C1 + j];
        }
        float o = xd[j] + fmaxf(u, 0.f);
        x1[j] = (o > 0.f) ? o : 0.01f * o;       // leaky_relu
    }
    float o2[C2];
#pragma unroll
    for (int k = 0; k < C2; ++k) o2[k] = 0.f;
#pragma unroll
    for (int j = 0; j < C1; ++j) {
        float xv = x1[j];
#pragma unroll
        for (int k = 0; k < C2; ++k) o2[k] += xv * V2[j*C2 + k];
    }
    float dk = 0.f, dq = 0.f;
#pragma unroll
    for (int k = 0; k < C2; ++k) { dk += o2[k]*KV[k]; dq += o2[k]*QV[k]; }
    __half* o = xs2h + ((size_t)node*C2)*2 + b;
#pragma unroll
    for (int k = 0; k < C2; ++k) o[2*k] = __float2half_rn(o2[k]);
    dotk2[node*2 + b] = dk; dotq2[node*2 + b] = dq;
}

// ---------------- layer-2 bucket aggregation (LDS accumulators) --------------
// block = one bucket of 32 dst nodes; 16 lanes per record; stride 65 bank-spread
#define A2STRIDE 65
__global__ __launch_bounds__(256) void k_baggr2(
        const float* __restrict__ we, const float* __restrict__ ab,
        const float* __restrict__ sc,
        const uint2* __restrict__ xsh, const float* __restrict__ dotk,
        const float* __restrict__ dotq,
        const uint2* __restrict__ recs, const unsigned* __restrict__ bktTot,
        const unsigned* __restrict__ bucketBase, float* __restrict__ aggrf) {
    __shared__ float A[32 * A2STRIDE];
    __shared__ float DK[32 * 2];
    int tid = threadIdx.x;
    int bkt = NBK1 + blockIdx.x;
    int nb0 = blockIdx.x << W2S;
    for (int i = tid; i < 32 * A2STRIDE; i += 256) A[i] = 0.f;
    for (int i = tid; i < 64; i += 256)
        DK[i] = (nb0*2 + i < 2*NN) ? dotk[nb0*2 + i] : 0.f;
    __syncthreads();
    unsigned cnt  = bktTot[bkt];
    unsigned base = bucketBase[bkt];
    int cp = tid & 15;
    float w0 = we[2*cp], w1 = we[2*cp+1];
    float ec = sc[1], bias = ab[0];
    unsigned i = tid >> 4;
    uint2 r = (i < cnt) ? recs[base + i] : make_uint2(0u, 0u);
    for (; i < cnt; i += 16) {
        uint2 rc = r;
        if (i + 16 < cnt) r = recs[base + i + 16];
        int src = rc.x & 0xffff;
        int dl  = rc.x >> 16;
        float ef = __uint_as_float(rc.y);
        float se0 = sigmoidf(ef * w0);
        float se1 = sigmoidf(ef * w1);
        float eb  = ef * ec + bias;
        float2 dq = *(const float2*)(dotq + src*2);
        float a0 = sigmoidf(DK[dl*2]   + dq.x + eb);
        float a1 = sigmoidf(DK[dl*2+1] + dq.y + eb);
        uint2 xr = xsh[(size_t)src*16 + cp];
        float2 f0 = __half22float2(__builtin_bit_cast(__half2, xr.x));
        float2 f1 = __half22float2(__builtin_bit_cast(__half2, xr.y));
        float* a = &A[dl*A2STRIDE + cp*4];
        ldsAddF(a + 0, a0 * se0 * f0.x);
        ldsAddF(a + 1, a1 * se0 * f0.y);
        ldsAddF(a + 2, a0 * se1 * f1.x);
        ldsAddF(a + 3, a1 * se1 * f1.y);
    }
    __syncthreads();
    for (int i2 = tid; i2 < 32*64; i2 += 256) {
        int node = nb0 + (i2 >> 6);
        if (node < NN) aggrf[(size_t)node*64 + (i2 & 63)] = A[(i2 >> 6)*A2STRIDE + (i2 & 63)];
    }
}

// ---------------- final: update2 -> fp32 out [b][node][c] --------------------
__global__ __launch_bounds__(256) void k_update2(
        const float* __restrict__ cat_w, const float* __restrict__ cat_b,
        const __half* __restrict__ xs2h, const float* __restrict__ aggr2f,
        float* __restrict__ out) {
    __shared__ float CW[2*C2*C2];
    __shared__ float CB[C2];
    int tid = threadIdx.x;
    for (int i = tid; i < 2*C2*C2; i += 256) CW[i] = cat_w[i];
    if (tid < C2) CB[tid] = cat_b[tid];
    __syncthreads();
    int bn = blockIdx.x * 256 + tid;
    if (bn >= NB) return;
    int b = (bn >= NN) ? 1 : 0;
    int node = bn - b*NN;
    const __half* xr = xs2h + ((size_t)node*C2)*2 + b;
    const float* agp = aggr2f + (size_t)node*64;
    float xd[C2], ag[C2];
#pragma unroll
    for (int i = 0; i < C2; ++i) xd[i] = __half2float(xr[2*i]);
#pragma unroll
    for (int i = 0; i < C2; ++i) ag[i] = agp[(i>>1)*4 + (i&1)*2 + b];
    float o[C2];
#pragma unroll
    for (int k = 0; k < C2; ++k) {
        float u = CB[k];
#pragma unroll
        for (int i = 0; i < C2; ++i) {
            u += xd[i] * CW[i*C2 + k];
            u += ag[i] * CW[(C2+i)*C2 + k];
        }
        o[k] = xd[k] + fmaxf(u, 0.f);
    }
    float4* dst = (float4*)(out + (size_t)bn * C2);
#pragma unroll
    for (int v = 0; v < 8; ++v)
        dst[v] = make_float4(o[4*v], o[4*v+1], o[4*v+2], o[4*v+3]);
}

extern "C" void kernel_launch(void* const* d_in, const int* in_sizes, int n_in,
                              void* d_out, int out_size, void* d_ws, size_t ws_size,
                              hipStream_t stream) {
    const float* X      = (const float*)d_in[0];
    const int*   ei0    = (const int*)d_in[1];
    const int*   ei1    = (const int*)d_in[2];
    const float* ew0    = (const float*)d_in[3];
    const float* ew1    = (const float*)d_in[4];
    // d_in[5], d_in[6]: res_n_id0/1 == arange(N) -> identity gather, unused
    const float* value1 = (const float*)d_in[7];
    const float* key1   = (const float*)d_in[8];
    const float* query1 = (const float*)d_in[9];
    const float* we1    = (const float*)d_in[10];
    const float* aw1    = (const float*)d_in[11];
    const float* ab1    = (const float*)d_in[12];
    const float* cw1    = (const float*)d_in[13];
    const float* cb1    = (const float*)d_in[14];
    const float* value2 = (const float*)d_in[15];
    const float* key2   = (const float*)d_in[16];
    const float* query2 = (const float*)d_in[17];
    const float* we2    = (const float*)d_in[18];
    const float* aw2    = (const float*)d_in[19];
    const float* ab2    = (const float*)d_in[20];
    const float* cw2    = (const float*)d_in[21];
    const float* cb2    = (const float*)d_in[22];
    float* ws  = (float*)d_ws;
    float* out = (float*)d_out;

    __half* xs1h = (__half*)(ws + OFF_XS1);
    __half* xs2h = (__half*)(ws + OFF_XS2);
    float* aggr1f = ws + OFF_AG1;
    float* aggr2f = ws + OFF_AG2;
    unsigned* blockCnt   = (unsigned*)(ws + OFF_BCNT);
    unsigned* bktTot     = (unsigned*)(ws + OFF_BTOT);
    unsigned* bucketBase = (unsigned*)(ws + OFF_BBASE);
    uint2*    recs       = (uint2*)(ws + OFF_RECS);

    k_sc<<<1, 64, 0, stream>>>(we1, aw1, we2, aw2, ws + OFF_SC);

    // node transform first (independent of binning)
    k_value1<<<(NB+255)/256, 256, 0, stream>>>(X, value1, key1, query1, aw1,
                                               xs1h, ws + OFF_DOTK1, ws + OFF_DOTQ1);

    // deterministic radix binning of both layers' edges
    k_cnt<<<NEBLK, 256, 0, stream>>>(ei0, ei1, blockCnt);
    k_scanBkt<<<NBKT, 128, 0, stream>>>(blockCnt, bktTot);
    k_scanTot<<<1, 1024, 0, stream>>>(bktTot, bucketBase);
    k_permute<<<NEBLK, 256, 0, stream>>>(ei0, ei1, ew0, ew1,
                                         blockCnt, bucketBase, recs);

    k_baggr1<<<NBK1, 256, 0, stream>>>(we1, ab1, ws + OFF_SC,
                                       (const uint2*)xs1h,
                                       ws + OFF_DOTK1, ws + OFF_DOTQ1,
                                       recs, bktTot, bucketBase, aggr1f);
    k_update1<<<(NB+255)/256, 256, 0, stream>>>(cw1, cb1, value2, key2, query2, aw2,
                                                xs1h, aggr1f,
                                                xs2h, ws + OFF_DOTK2, ws + OFF_DOTQ2);
    k_baggr2<<<NBK2, 256, 0, stream>>>(we2, ab2, ws + OFF_SC,
                                       (const uint2*)xs2h,
                                       ws + OFF_DOTK2, ws + OFF_DOTQ2,
                                       recs, bktTot, bucketBase, aggr2f);
    k_update2<<<(NB+255)/256, 256, 0, stream>>>(cw2, cb2, xs2h, aggr2f, out);
}

// Round 5
// 417.294 us; speedup vs baseline: 1.8310x; 1.8310x over previous
//
#include <hip/hip_runtime.h>
#include <hip/hip_fp16.h>

#define BB   2
#define NN   50000
#define EE   800000
#define INCH 64
#define C1   16
#define C2   32
#define NB   (BB*NN)

// radix binning geometry
#define W1S   6                      // layer-1 bucket = 64 dst nodes
#define W2S   5                      // layer-2 bucket = 32 dst nodes
#define NBK1  ((NN + 63) >> 6)       // 782
#define NBK2  ((NN + 31) >> 5)       // 1563
#define NBKT  (NBK1 + NBK2)          // 2345
#define EB    16384                  // edges per binning block
#define NEBLK ((2*EE + EB - 1) / EB) // 98

// workspace layout (float-unit offsets)
#define OFF_XS1   0                          // NB*C1 halves
#define OFF_XS2   (OFF_XS1 + NB*C1/2)        // NB*C2 halves
#define OFF_DOTK1 (OFF_XS2 + NB*C2/2)
#define OFF_DOTQ1 (OFF_DOTK1 + NB)
#define OFF_DOTK2 (OFF_DOTQ1 + NB)
#define OFF_DOTQ2 (OFF_DOTK2 + NB)
#define OFF_AG1   (OFF_DOTQ2 + NB)           // NN*32 floats
#define OFF_AG2   (OFF_AG1 + NN*32)          // NN*64 floats
#define OFF_BCNT  (OFF_AG2 + NN*64)          // NEBLK*NBKT u32
#define OFF_BTOT  (OFF_BCNT + NEBLK*NBKT)    // NBKT u32
#define OFF_BBASE (OFF_BTOT + NBKT)          // NBKT u32
#define OFF_START (OFF_BBASE + NBKT)         // NODE2 u32 (layer1 @ [0,NN), layer2 @ [NN,2NN))
#define OFF_DEG   (OFF_START + 2*NN)         // NODE2 u32
#define OFF_SC    (OFF_DEG + 2*NN)           // 2 floats
#define OFF_RECS2 (OFF_SC + 2)               // 2*EE uint2 (dst-sorted records)
#define OFF_RECS  (OFF_RECS2 + 2*EE*2)       // 2*EE uint2 (bucket-grouped); MSG aliases here
// MSG = EE*16 uint2 = EE*32 floats, starts at OFF_RECS (recs dead after k_sortb)

__device__ __forceinline__ float sigmoidf(float x) {
    return 1.0f / (1.0f + __expf(-x));
}

// ---------------- tiny scalar precompute -------------------------------------
__global__ void k_sc(const float* __restrict__ we1, const float* __restrict__ aw1,
                     const float* __restrict__ we2, const float* __restrict__ aw2,
                     float* __restrict__ sc) {
    if (threadIdx.x == 0) {
        float e = 0.f;
        for (int j = 0; j < C1; ++j) e += we1[j] * aw1[2*C1+j];
        sc[0] = e;
    }
    if (threadIdx.x == 1) {
        float e = 0.f;
        for (int j = 0; j < C2; ++j) e += we2[j] * aw2[2*C2+j];
        sc[1] = e;
    }
}

// ---------------- pass A: per-(block,bucket) histogram -----------------------
__global__ __launch_bounds__(256) void k_cnt(
        const int* __restrict__ ei0, const int* __restrict__ ei1,
        unsigned* __restrict__ blockCnt) {
    __shared__ unsigned h[NBKT];
    int tid = threadIdx.x;
    for (int i = tid; i < NBKT; i += 256) h[i] = 0u;
    __syncthreads();
    int base = blockIdx.x * EB;
#pragma unroll 4
    for (int j = 0; j < EB/256; ++j) {
        int t = base + j*256 + tid;
        if (t < 2*EE) {
            int bkt;
            if (t < EE) { int dst = ei0[EE + t];      bkt = dst >> W1S; }
            else        { int dst = ei1[EE + t - EE]; bkt = NBK1 + (dst >> W2S); }
            atomicAdd(&h[bkt], 1u);
        }
    }
    __syncthreads();
    unsigned* o = blockCnt + (size_t)blockIdx.x * NBKT;
    for (int i = tid; i < NBKT; i += 256) o[i] = h[i];
}

// ---------------- pass B1: scan over blocks, per bucket (in-place) -----------
__global__ __launch_bounds__(128) void k_scanBkt(
        unsigned* __restrict__ blockCnt, unsigned* __restrict__ bktTot) {
    __shared__ unsigned s[128];
    int tid = threadIdx.x;
    int bkt = blockIdx.x;
    unsigned v = (tid < NEBLK) ? blockCnt[(size_t)tid * NBKT + bkt] : 0u;
    s[tid] = v;
    __syncthreads();
    for (int o = 1; o < 128; o <<= 1) {
        unsigned t = (tid >= o) ? s[tid - o] : 0u;
        __syncthreads();
        s[tid] += t;
        __syncthreads();
    }
    if (tid < NEBLK) blockCnt[(size_t)tid * NBKT + bkt] = s[tid] - v;  // exclusive
    if (tid == 127) bktTot[bkt] = s[127];
}

// ---------------- pass B2: scan bucket totals -> bucket bases ----------------
__global__ __launch_bounds__(1024) void k_scanTot(
        const unsigned* __restrict__ bktTot, unsigned* __restrict__ bucketBase) {
    __shared__ unsigned s[1024];
    int tid = threadIdx.x;
    int base = tid * 3;
    unsigned a0 = (base + 0 < NBKT) ? bktTot[base + 0] : 0u;
    unsigned a1 = (base + 1 < NBKT) ? bktTot[base + 1] : 0u;
    unsigned a2 = (base + 2 < NBKT) ? bktTot[base + 2] : 0u;
    unsigned l = a0 + a1 + a2;
    s[tid] = l;
    __syncthreads();
    for (int o = 1; o < 1024; o <<= 1) {
        unsigned t = (tid >= o) ? s[tid - o] : 0u;
        __syncthreads();
        s[tid] += t;
        __syncthreads();
    }
    unsigned ex = s[tid] - l;
    if (base + 0 < NBKT) bucketBase[base + 0] = ex;
    if (base + 1 < NBKT) bucketBase[base + 1] = ex + a0;
    if (base + 2 < NBKT) bucketBase[base + 2] = ex + a0 + a1;
}

// ---------------- pass C: permute edge records into bucket-grouped order -----
__global__ __launch_bounds__(256) void k_permute(
        const int* __restrict__ ei0, const int* __restrict__ ei1,
        const float* __restrict__ ew0, const float* __restrict__ ew1,
        const unsigned* __restrict__ blockOff, const unsigned* __restrict__ bucketBase,
        uint2* __restrict__ recs) {
    __shared__ unsigned off[NBKT];
    __shared__ unsigned cur[NBKT];
    int tid = threadIdx.x;
    const unsigned* bo = blockOff + (size_t)blockIdx.x * NBKT;
    for (int i = tid; i < NBKT; i += 256) { off[i] = bo[i] + bucketBase[i]; cur[i] = 0u; }
    __syncthreads();
    int base = blockIdx.x * EB;
    for (int j = 0; j < EB/256; ++j) {
        int t = base + j*256 + tid;
        if (t >= 2*EE) break;
        int bkt, dl, src; float ef;
        if (t < EE) {
            int dst = ei0[EE + t];
            bkt = dst >> W1S; dl = dst & 63;
            src = ei0[t]; ef = ew0[t];
        } else {
            int e = t - EE;
            int dst = ei1[EE + e];
            bkt = NBK1 + (dst >> W2S); dl = dst & 31;
            src = ei1[e]; ef = ew1[e];
        }
        unsigned pos = off[bkt] + atomicAdd(&cur[bkt], 1u);
        recs[pos] = make_uint2((unsigned)src | ((unsigned)dl << 16), __float_as_uint(ef));
    }
}

// ---------------- pass D: per-bucket counting sort by dst -> exact CSR -------
// two global passes over the bucket's records (2nd pass L2-hot); writes
// recs2 = (src | dst<<16, ef) dst-grouped, plus per-node start/deg.
__global__ __launch_bounds__(256) void k_sortb(
        const uint2* __restrict__ recs, const unsigned* __restrict__ bktTot,
        const unsigned* __restrict__ bucketBase,
        uint2* __restrict__ recs2, unsigned* __restrict__ startA,
        unsigned* __restrict__ degA) {
    __shared__ unsigned h[64], sOff[64], cur[64];
    int tid = threadIdx.x;
    int bkt = blockIdx.x;
    int lay1 = (bkt < NBK1) ? 1 : 0;
    int ndl  = lay1 ? 64 : 32;
    int nodeBase = lay1 ? (bkt << W1S) : ((bkt - NBK1) << W2S);
    int layOff   = lay1 ? 0 : NN;
    if (tid < 64) h[tid] = 0u;
    __syncthreads();
    unsigned cnt = bktTot[bkt], base = bucketBase[bkt];
    for (unsigned i = tid; i < cnt; i += 256)
        atomicAdd(&h[recs[base + i].x >> 16], 1u);
    __syncthreads();
    if (tid == 0) {
        unsigned run = 0;
        for (int d = 0; d < ndl; ++d) { sOff[d] = run; run += h[d]; }
    }
    __syncthreads();
    if (tid < ndl) {
        cur[tid] = sOff[tid];
        int node = nodeBase + tid;
        if (node < NN) {
            startA[layOff + node] = base + sOff[tid];
            degA[layOff + node]   = h[tid];
        }
    }
    __syncthreads();
    for (unsigned i = tid; i < cnt; i += 256) {
        uint2 r = recs[base + i];
        unsigned dl  = r.x >> 16;
        unsigned src = r.x & 0xffffu;
        unsigned pos = atomicAdd(&cur[dl], 1u);
        unsigned dst = (unsigned)nodeBase + dl;
        recs2[base + pos] = make_uint2(src | (dst << 16), r.y);
    }
}

// ---------------- layer 1: xs1 = X @ value1 (half-packed out) ----------------
__global__ __launch_bounds__(256) void k_value1(
        const float* __restrict__ X, const float* __restrict__ value1,
        const float* __restrict__ key1, const float* __restrict__ query1,
        const float* __restrict__ aw1,
        __half* __restrict__ xs1h, float* __restrict__ dotk1, float* __restrict__ dotq1) {
    __shared__ float W[INCH*C1];
    __shared__ float KV[C1], QV[C1];
    int tid = threadIdx.x;
    for (int i = tid; i < INCH*C1; i += 256) W[i] = value1[i];
    if (tid < C1) {
        float kv = 0.f, qv = 0.f;
#pragma unroll
        for (int j = 0; j < C1; ++j) {
            kv += key1[tid*C1+j]   * aw1[j];
            qv += query1[tid*C1+j] * aw1[C1+j];
        }
        KV[tid] = kv; QV[tid] = qv;
    }
    __syncthreads();
    int bn = blockIdx.x * 256 + tid;
    if (bn >= NB) return;
    int b = (bn >= NN) ? 1 : 0;
    int node = bn - b*NN;
    const float4* Xr = (const float4*)(X + (size_t)bn * INCH);
    float acc[C1];
#pragma unroll
    for (int j = 0; j < C1; ++j) acc[j] = 0.f;
#pragma unroll
    for (int v = 0; v < 16; ++v) {
        float4 p = Xr[v];
        float x4[4] = {p.x, p.y, p.z, p.w};
#pragma unroll
        for (int h = 0; h < 4; ++h) {
            int i = v*4 + h;
            float xv = x4[h];
#pragma unroll
            for (int j = 0; j < C1; ++j) acc[j] += xv * W[i*C1+j];
        }
    }
    float dk = 0.f, dq = 0.f;
#pragma unroll
    for (int j = 0; j < C1; ++j) { dk += acc[j]*KV[j]; dq += acc[j]*QV[j]; }
    __half* o = xs1h + ((size_t)node * C1) * 2 + b;
#pragma unroll
    for (int j = 0; j < C1; ++j) o[2*j] = __float2half_rn(acc[j]);
    dotk1[node*2 + b] = dk; dotq1[node*2 + b] = dq;
}

// ---------------- layer-1 message materialization: edge-parallel, loop-free --
__global__ __launch_bounds__(256) void k_gath1(
        const uint2* __restrict__ recs2, const float* __restrict__ we,
        const float* __restrict__ ab, const float* __restrict__ sc,
        const uint2* __restrict__ xsh, const float* __restrict__ dotk,
        const float* __restrict__ dotq, uint2* __restrict__ msg) {
    int t = blockIdx.x * 256 + threadIdx.x;      // grid exact: EE*8 threads
    int p = t >> 3, cp = t & 7;
    uint2 rec = recs2[p];
    int src = rec.x & 0xffff, dst = rec.x >> 16;
    float ef = __uint_as_float(rec.y);
    float se0 = sigmoidf(ef * we[2*cp]);
    float se1 = sigmoidf(ef * we[2*cp+1]);
    float eb  = ef * sc[0] + ab[0];
    float2 dq = *(const float2*)(dotq + src*2);
    float2 dk = *(const float2*)(dotk + dst*2);
    float a0 = sigmoidf(dk.x + dq.x + eb);
    float a1 = sigmoidf(dk.y + dq.y + eb);
    uint2 xr = xsh[(size_t)src*8 + cp];
    float2 f0 = __half22float2(__builtin_bit_cast(__half2, xr.x));
    float2 f1 = __half22float2(__builtin_bit_cast(__half2, xr.y));
    __half2 m0 = __floats2half2_rn(a0*se0*f0.x, a1*se0*f0.y);
    __half2 m1 = __floats2half2_rn(a0*se1*f1.x, a1*se1*f1.y);
    msg[(size_t)p*8 + cp] = make_uint2(__builtin_bit_cast(unsigned, m0),
                                       __builtin_bit_cast(unsigned, m1));
}

// ---------------- layer-1 segmented reduce: streaming, no gathers ------------
__global__ __launch_bounds__(256) void k_red1(
        const unsigned* __restrict__ startA, const unsigned* __restrict__ degA,
        const uint2* __restrict__ msg, float* __restrict__ aggrf) {
    int t = blockIdx.x * 256 + threadIdx.x;
    int node = t >> 3, cp = t & 7;
    if (node >= NN) return;
    unsigned s = startA[node];
    unsigned n = degA[node];
    float a0 = 0.f, a1 = 0.f, a2 = 0.f, a3 = 0.f;
    const uint2* mp = msg + (size_t)s*8 + cp;
    for (unsigned i = 0; i < n; ++i) {
        uint2 v = mp[(size_t)i*8];
        float2 f0 = __half22float2(__builtin_bit_cast(__half2, v.x));
        float2 f1 = __half22float2(__builtin_bit_cast(__half2, v.y));
        a0 += f0.x; a1 += f0.y; a2 += f1.x; a3 += f1.y;
    }
    ((float4*)aggrf)[(size_t)node*8 + cp] = make_float4(a0, a1, a2, a3);
}

// ---------------- fused: update1 + leaky_relu + xs2 = X1 @ value2 ------------
__global__ __launch_bounds__(256) void k_update1(
        const float* __restrict__ cat_w, const float* __restrict__ cat_b,
        const float* __restrict__ value2,
        const float* __restrict__ key2, const float* __restrict__ query2,
        const float* __restrict__ aw2,
        const __half* __restrict__ xs1h, const float* __restrict__ aggr1f,
        __half* __restrict__ xs2h, float* __restrict__ dotk2, float* __restrict__ dotq2) {
    __shared__ float CW[2*C1*C1];
    __shared__ float CB[C1];
    __shared__ float V2[C1*C2];
    __shared__ float KV[C2], QV[C2];
    int tid = threadIdx.x;
    for (int i = tid; i < 2*C1*C1; i += 256) CW[i] = cat_w[i];
    for (int i = tid; i < C1*C2;   i += 256) V2[i] = value2[i];
    if (tid < C1) CB[tid] = cat_b[tid];
    if (tid < C2) {
        float kv = 0.f;
#pragma unroll
        for (int j = 0; j < C2; ++j) kv += key2[tid*C2+j] * aw2[j];
        KV[tid] = kv;
    } else if (tid < 2*C2) {
        int c = tid - C2;
        float qv = 0.f;
#pragma unroll
        for (int j = 0; j < C2; ++j) qv += query2[c*C2+j] * aw2[C2+j];
        QV[c] = qv;
    }
    __syncthreads();
    int bn = blockIdx.x * 256 + tid;
    if (bn >= NB) return;
    int b = (bn >= NN) ? 1 : 0;
    int node = bn - b*NN;
    const __half* xr = xs1h + ((size_t)node*C1)*2 + b;
    const float* agp = aggr1f + (size_t)node*32;
    float xd[C1], ag[C1];
#pragma unroll
    for (int i = 0; i < C1; ++i) xd[i] = __half2float(xr[2*i]);
#pragma unroll
    for (int i = 0; i < C1; ++i) ag[i] = agp[(i>>1)*4 + (i&1)*2 + b];
    float x1[C1];
#pragma unroll
    for (int j = 0; j < C1; ++j) {
        float u = CB[j];
#pragma unroll
        for (int i = 0; i < C1; ++i) {
            u += xd[i] * CW[i*C1 + j];
            u += ag[i] * CW[(C1+i)*C1 + j];
        }
        float o = xd[j] + fmaxf(u, 0.f);
        x1[j] = (o > 0.f) ? o : 0.01f * o;       // leaky_relu
    }
    float o2[C2];
#pragma unroll
    for (int k = 0; k < C2; ++k) o2[k] = 0.f;
#pragma unroll
    for (int j = 0; j < C1; ++j) {
        float xv = x1[j];
#pragma unroll
        for (int k = 0; k < C2; ++k) o2[k] += xv * V2[j*C2 + k];
    }
    float dk = 0.f, dq = 0.f;
#pragma unroll
    for (int k = 0; k < C2; ++k) { dk += o2[k]*KV[k]; dq += o2[k]*QV[k]; }
    __half* o = xs2h + ((size_t)node*C2)*2 + b;
#pragma unroll
    for (int k = 0; k < C2; ++k) o[2*k] = __float2half_rn(o2[k]);
    dotk2[node*2 + b] = dk; dotq2[node*2 + b] = dq;
}

// ---------------- layer-2 message materialization: edge-parallel, loop-free --
__global__ __launch_bounds__(256) void k_gath2(
        const uint2* __restrict__ recs2, const float* __restrict__ we,
        const float* __restrict__ ab, const float* __restrict__ sc,
        const uint2* __restrict__ xsh, const float* __restrict__ dotk,
        const float* __restrict__ dotq, uint2* __restrict__ msg) {
    int t = blockIdx.x * 256 + threadIdx.x;      // grid exact: EE*16 threads
    int p = t >> 4, cp = t & 15;
    uint2 rec = recs2[EE + p];                   // layer-2 records live at [EE, 2EE)
    int src = rec.x & 0xffff, dst = rec.x >> 16;
    float ef = __uint_as_float(rec.y);
    float se0 = sigmoidf(ef * we[2*cp]);
    float se1 = sigmoidf(ef * we[2*cp+1]);
    float eb  = ef * sc[1] + ab[0];
    float2 dq = *(const float2*)(dotq + src*2);
    float2 dk = *(const float2*)(dotk + dst*2);
    float a0 = sigmoidf(dk.x + dq.x + eb);
    float a1 = sigmoidf(dk.y + dq.y + eb);
    uint2 xr = xsh[(size_t)src*16 + cp];
    float2 f0 = __half22float2(__builtin_bit_cast(__half2, xr.x));
    float2 f1 = __half22float2(__builtin_bit_cast(__half2, xr.y));
    __half2 m0 = __floats2half2_rn(a0*se0*f0.x, a1*se0*f0.y);
    __half2 m1 = __floats2half2_rn(a0*se1*f1.x, a1*se1*f1.y);
    msg[(size_t)p*16 + cp] = make_uint2(__builtin_bit_cast(unsigned, m0),
                                        __builtin_bit_cast(unsigned, m1));
}

// ---------------- layer-2 segmented reduce: streaming, no gathers ------------
__global__ __launch_bounds__(256) void k_red2(
        const unsigned* __restrict__ startA, const unsigned* __restrict__ degA,
        const uint2* __restrict__ msg, float* __restrict__ aggrf) {
    int t = blockIdx.x * 256 + threadIdx.x;
    int node = t >> 4, cp = t & 15;
    if (node >= NN) return;
    unsigned s = startA[NN + node] - EE;         // into layer-2 msg region
    unsigned n = degA[NN + node];
    float a0 = 0.f, a1 = 0.f, a2 = 0.f, a3 = 0.f;
    const uint2* mp = msg + (size_t)s*16 + cp;
    for (unsigned i = 0; i < n; ++i) {
        uint2 v = mp[(size_t)i*16];
        float2 f0 = __half22float2(__builtin_bit_cast(__half2, v.x));
        float2 f1 = __half22float2(__builtin_bit_cast(__half2, v.y));
        a0 += f0.x; a1 += f0.y; a2 += f1.x; a3 += f1.y;
    }
    ((float4*)aggrf)[(size_t)node*16 + cp] = make_float4(a0, a1, a2, a3);
}

// ---------------- final: update2 -> fp32 out [b][node][c] --------------------
__global__ __launch_bounds__(256) void k_update2(
        const float* __restrict__ cat_w, const float* __restrict__ cat_b,
        const __half* __restrict__ xs2h, const float* __restrict__ aggr2f,
        float* __restrict__ out) {
    __shared__ float CW[2*C2*C2];
    __shared__ float CB[C2];
    int tid = threadIdx.x;
    for (int i = tid; i < 2*C2*C2; i += 256) CW[i] = cat_w[i];
    if (tid < C2) CB[tid] = cat_b[tid];
    __syncthreads();
    int bn = blockIdx.x * 256 + tid;
    if (bn >= NB) return;
    int b = (bn >= NN) ? 1 : 0;
    int node = bn - b*NN;
    const __half* xr = xs2h + ((size_t)node*C2)*2 + b;
    const float* agp = aggr2f + (size_t)node*64;
    float xd[C2], ag[C2];
#pragma unroll
    for (int i = 0; i < C2; ++i) xd[i] = __half2float(xr[2*i]);
#pragma unroll
    for (int i = 0; i < C2; ++i) ag[i] = agp[(i>>1)*4 + (i&1)*2 + b];
    float o[C2];
#pragma unroll
    for (int k = 0; k < C2; ++k) {
        float u = CB[k];
#pragma unroll
        for (int i = 0; i < C2; ++i) {
            u += xd[i] * CW[i*C2 + k];
            u += ag[i] * CW[(C2+i)*C2 + k];
        }
        o[k] = xd[k] + fmaxf(u, 0.f);
    }
    float4* dst = (float4*)(out + (size_t)bn * C2);
#pragma unroll
    for (int v = 0; v < 8; ++v)
        dst[v] = make_float4(o[4*v], o[4*v+1], o[4*v+2], o[4*v+3]);
}

extern "C" void kernel_launch(void* const* d_in, const int* in_sizes, int n_in,
                              void* d_out, int out_size, void* d_ws, size_t ws_size,
                              hipStream_t stream) {
    const float* X      = (const float*)d_in[0];
    const int*   ei0    = (const int*)d_in[1];
    const int*   ei1    = (const int*)d_in[2];
    const float* ew0    = (const float*)d_in[3];
    const float* ew1    = (const float*)d_in[4];
    // d_in[5], d_in[6]: res_n_id0/1 == arange(N) -> identity gather, unused
    const float* value1 = (const float*)d_in[7];
    const float* key1   = (const float*)d_in[8];
    const float* query1 = (const float*)d_in[9];
    const float* we1    = (const float*)d_in[10];
    const float* aw1    = (const float*)d_in[11];
    const float* ab1    = (const float*)d_in[12];
    const float* cw1    = (const float*)d_in[13];
    const float* cb1    = (const float*)d_in[14];
    const float* value2 = (const float*)d_in[15];
    const float* key2   = (const float*)d_in[16];
    const float* query2 = (const float*)d_in[17];
    const float* we2    = (const float*)d_in[18];
    const float* aw2    = (const float*)d_in[19];
    const float* ab2    = (const float*)d_in[20];
    const float* cw2    = (const float*)d_in[21];
    const float* cb2    = (const float*)d_in[22];
    float* ws  = (float*)d_ws;
    float* out = (float*)d_out;

    __half* xs1h = (__half*)(ws + OFF_XS1);
    __half* xs2h = (__half*)(ws + OFF_XS2);
    float* aggr1f = ws + OFF_AG1;
    float* aggr2f = ws + OFF_AG2;
    unsigned* blockCnt   = (unsigned*)(ws + OFF_BCNT);
    unsigned* bktTot     = (unsigned*)(ws + OFF_BTOT);
    unsigned* bucketBase = (unsigned*)(ws + OFF_BBASE);
    unsigned* startA     = (unsigned*)(ws + OFF_START);
    unsigned* degA       = (unsigned*)(ws + OFF_DEG);
    uint2*    recs2      = (uint2*)(ws + OFF_RECS2);
    uint2*    recs       = (uint2*)(ws + OFF_RECS);
    uint2*    msg        = (uint2*)(ws + OFF_RECS);   // aliases recs (dead after k_sortb)

    k_sc<<<1, 64, 0, stream>>>(we1, aw1, we2, aw2, ws + OFF_SC);

    // node transform (independent of binning)
    k_value1<<<(NB+255)/256, 256, 0, stream>>>(X, value1, key1, query1, aw1,
                                               xs1h, ws + OFF_DOTK1, ws + OFF_DOTQ1);

    // deterministic two-level sort of both layers' edges by dst
    k_cnt<<<NEBLK, 256, 0, stream>>>(ei0, ei1, blockCnt);
    k_scanBkt<<<NBKT, 128, 0, stream>>>(blockCnt, bktTot);
    k_scanTot<<<1, 1024, 0, stream>>>(bktTot, bucketBase);
    k_permute<<<NEBLK, 256, 0, stream>>>(ei0, ei1, ew0, ew1,
                                         blockCnt, bucketBase, recs);
    k_sortb<<<NBKT, 256, 0, stream>>>(recs, bktTot, bucketBase,
                                      recs2, startA, degA);

    // layer 1: materialize messages edge-parallel, then streaming reduce
    k_gath1<<<(EE*8)/256, 256, 0, stream>>>(recs2, we1, ab1, ws + OFF_SC,
                                            (const uint2*)xs1h,
                                            ws + OFF_DOTK1, ws + OFF_DOTQ1, msg);
    k_red1<<<(NN*8+255)/256, 256, 0, stream>>>(startA, degA, msg, aggr1f);
    k_update1<<<(NB+255)/256, 256, 0, stream>>>(cw1, cb1, value2, key2, query2, aw2,
                                                xs1h, aggr1f,
                                                xs2h, ws + OFF_DOTK2, ws + OFF_DOTQ2);

    // layer 2
    k_gath2<<<(EE*16)/256, 256, 0, stream>>>(recs2, we2, ab2, ws + OFF_SC,
                                             (const uint2*)xs2h,
                                             ws + OFF_DOTK2, ws + OFF_DOTQ2, msg);
    k_red2<<<(NN*16+255)/256, 256, 0, stream>>>(startA, degA, msg, aggr2f);
    k_update2<<<(NB+255)/256, 256, 0, stream>>>(cw2, cb2, xs2h, aggr2f, out);
}

// Round 7
// 364.533 us; speedup vs baseline: 2.0960x; 1.1447x over previous
//
#include <hip/hip_runtime.h>
#include <hip/hip_fp16.h>

#define BB   2
#define NN   50000
#define EE   800000
#define INCH 64
#define C1   16
#define C2   32
#define NB   (BB*NN)

// radix binning geometry
#define W1S   6                      // layer-1 bucket = 64 dst nodes
#define W2S   5                      // layer-2 bucket = 32 dst nodes
#define NBK1  ((NN + 63) >> 6)       // 782
#define NBK2  ((NN + 31) >> 5)       // 1563
#define NBKT  (NBK1 + NBK2)          // 2345
#define EB    4096                   // edges per binning block
#define TPB   1024                   // threads per binning block
#define NEBLK ((2*EE + EB - 1) / EB) // 391

// workspace layout (float-unit offsets)
#define OFF_XS1   0                          // NB*C1 halves
#define OFF_XS2   (OFF_XS1 + NB*C1/2)        // NB*C2 halves
#define OFF_DOTK1 (OFF_XS2 + NB*C2/2)
#define OFF_DOTQ1 (OFF_DOTK1 + NB)
#define OFF_DOTK2 (OFF_DOTQ1 + NB)
#define OFF_DOTQ2 (OFF_DOTK2 + NB)
#define OFF_AG1   (OFF_DOTQ2 + NB)           // NN*32 floats
#define OFF_AG2   (OFF_AG1 + NN*32)          // NN*64 floats
#define OFF_BTOT  (OFF_AG2 + NN*64)          // NBKT u32
#define OFF_BBASE (OFF_BTOT + NBKT)          // NBKT u32
#define OFF_START (OFF_BBASE + NBKT)         // 2NN u32 (layer1 @ [0,NN), layer2 @ [NN,2NN))
#define OFF_DEG   (OFF_START + 2*NN)         // 2NN u32
#define OFF_SC    (OFF_DEG + 2*NN)           // 2 floats
#define OFF_RECS2 (OFF_SC + 2)               // 2*EE uint2 (dst-sorted records)
// alias region: EE*16 uint2 = EE*32 floats total (the layer-2 msg buffer).
// recs (2*EE uint2) at its start, BCNT (NEBLK*NBKT u32) after recs.
// Both are dead before msg is written.
#define OFF_REGION (OFF_RECS2 + 2*EE*2)
#define OFF_RECS   OFF_REGION
#define OFF_BCNT   (OFF_REGION + 2*EE*2)

__device__ __forceinline__ float sigmoidf(float x) {
    return 1.0f / (1.0f + __expf(-x));
}

// ---------------- tiny scalar precompute -------------------------------------
__global__ void k_sc(const float* __restrict__ we1, const float* __restrict__ aw1,
                     const float* __restrict__ we2, const float* __restrict__ aw2,
                     float* __restrict__ sc) {
    if (threadIdx.x == 0) {
        float e = 0.f;
        for (int j = 0; j < C1; ++j) e += we1[j] * aw1[2*C1+j];
        sc[0] = e;
    }
    if (threadIdx.x == 1) {
        float e = 0.f;
        for (int j = 0; j < C2; ++j) e += we2[j] * aw2[2*C2+j];
        sc[1] = e;
    }
}

// ---------------- pass A: per-(block,bucket) histogram -----------------------
__global__ __launch_bounds__(TPB) void k_cnt(
        const int* __restrict__ ei0, const int* __restrict__ ei1,
        unsigned* __restrict__ blockCnt) {
    __shared__ unsigned h[NBKT];
    int tid = threadIdx.x;
    for (int i = tid; i < NBKT; i += TPB) h[i] = 0u;
    __syncthreads();
    int base = blockIdx.x * EB;
#pragma unroll
    for (int j = 0; j < EB/TPB; ++j) {
        int t = base + j*TPB + tid;
        if (t < 2*EE) {
            int bkt;
            if (t < EE) { int dst = ei0[EE + t];      bkt = dst >> W1S; }
            else        { int dst = ei1[EE + t - EE]; bkt = NBK1 + (dst >> W2S); }
            atomicAdd(&h[bkt], 1u);
        }
    }
    __syncthreads();
    unsigned* o = blockCnt + (size_t)blockIdx.x * NBKT;
    for (int i = tid; i < NBKT; i += TPB) o[i] = h[i];
}

// ---------------- pass B1: scan over blocks, per bucket (in-place) -----------
// 512-thread scan covers NEBLK=391
__global__ __launch_bounds__(512) void k_scanBkt(
        unsigned* __restrict__ blockCnt, unsigned* __restrict__ bktTot) {
    __shared__ unsigned s[512];
    int tid = threadIdx.x;
    int bkt = blockIdx.x;
    unsigned v = (tid < NEBLK) ? blockCnt[(size_t)tid * NBKT + bkt] : 0u;
    s[tid] = v;
    __syncthreads();
    for (int o = 1; o < 512; o <<= 1) {
        unsigned t = (tid >= o) ? s[tid - o] : 0u;
        __syncthreads();
        s[tid] += t;
        __syncthreads();
    }
    if (tid < NEBLK) blockCnt[(size_t)tid * NBKT + bkt] = s[tid] - v;  // exclusive
    if (tid == 511) bktTot[bkt] = s[511];
}

// ---------------- pass B2: scan bucket totals -> bucket bases ----------------
__global__ __launch_bounds__(1024) void k_scanTot(
        const unsigned* __restrict__ bktTot, unsigned* __restrict__ bucketBase) {
    __shared__ unsigned s[1024];
    int tid = threadIdx.x;
    int base = tid * 3;
    unsigned a0 = (base + 0 < NBKT) ? bktTot[base + 0] : 0u;
    unsigned a1 = (base + 1 < NBKT) ? bktTot[base + 1] : 0u;
    unsigned a2 = (base + 2 < NBKT) ? bktTot[base + 2] : 0u;
    unsigned l = a0 + a1 + a2;
    s[tid] = l;
    __syncthreads();
    for (int o = 1; o < 1024; o <<= 1) {
        unsigned t = (tid >= o) ? s[tid - o] : 0u;
        __syncthreads();
        s[tid] += t;
        __syncthreads();
    }
    unsigned ex = s[tid] - l;
    if (base + 0 < NBKT) bucketBase[base + 0] = ex;
    if (base + 1 < NBKT) bucketBase[base + 1] = ex + a0;
    if (base + 2 < NBKT) bucketBase[base + 2] = ex + a0 + a1;
}

// ---------------- pass C: permute edge records into bucket-grouped order -----
__global__ __launch_bounds__(TPB) void k_permute(
        const int* __restrict__ ei0, const int* __restrict__ ei1,
        const float* __restrict__ ew0, const float* __restrict__ ew1,
        const unsigned* __restrict__ blockOff, const unsigned* __restrict__ bucketBase,
        uint2* __restrict__ recs) {
    __shared__ unsigned off[NBKT];
    __shared__ unsigned cur[NBKT];
    int tid = threadIdx.x;
    const unsigned* bo = blockOff + (size_t)blockIdx.x * NBKT;
    for (int i = tid; i < NBKT; i += TPB) { off[i] = bo[i] + bucketBase[i]; cur[i] = 0u; }
    __syncthreads();
    int base = blockIdx.x * EB;
#pragma unroll
    for (int j = 0; j < EB/TPB; ++j) {
        int t = base + j*TPB + tid;
        if (t >= 2*EE) break;
        int bkt, dl, src; float ef;
        if (t < EE) {
            int dst = ei0[EE + t];
            bkt = dst >> W1S; dl = dst & 63;
            src = ei0[t]; ef = ew0[t];
        } else {
            int e = t - EE;
            int dst = ei1[EE + e];
            bkt = NBK1 + (dst >> W2S); dl = dst & 31;
            src = ei1[e]; ef = ew1[e];
        }
        unsigned pos = off[bkt] + atomicAdd(&cur[bkt], 1u);
        recs[pos] = make_uint2((unsigned)src | ((unsigned)dl << 16), __float_as_uint(ef));
    }
}

// ---------------- pass D: per-bucket counting sort by dst -> exact CSR -------
__global__ __launch_bounds__(256) void k_sortb(
        const uint2* __restrict__ recs, const unsigned* __restrict__ bktTot,
        const unsigned* __restrict__ bucketBase,
        uint2* __restrict__ recs2, unsigned* __restrict__ startA,
        unsigned* __restrict__ degA) {
    __shared__ unsigned h[64], sOff[64], cur[64];
    int tid = threadIdx.x;
    int bkt = blockIdx.x;
    int lay1 = (bkt < NBK1) ? 1 : 0;
    int ndl  = lay1 ? 64 : 32;
    int nodeBase = lay1 ? (bkt << W1S) : ((bkt - NBK1) << W2S);
    int layOff   = lay1 ? 0 : NN;
    if (tid < 64) h[tid] = 0u;
    __syncthreads();
    unsigned cnt = bktTot[bkt], base = bucketBase[bkt];
    for (unsigned i = tid; i < cnt; i += 256)
        atomicAdd(&h[recs[base + i].x >> 16], 1u);
    __syncthreads();
    if (tid == 0) {
        unsigned run = 0;
        for (int d = 0; d < ndl; ++d) { sOff[d] = run; run += h[d]; }
    }
    __syncthreads();
    if (tid < ndl) {
        cur[tid] = sOff[tid];
        int node = nodeBase + tid;
        if (node < NN) {
            startA[layOff + node] = base + sOff[tid];
            degA[layOff + node]   = h[tid];
        }
    }
    __syncthreads();
    for (unsigned i = tid; i < cnt; i += 256) {
        uint2 r = recs[base + i];
        unsigned dl  = r.x >> 16;
        unsigned src = r.x & 0xffffu;
        unsigned pos = atomicAdd(&cur[dl], 1u);
        unsigned dst = (unsigned)nodeBase + dl;
        recs2[base + pos] = make_uint2(src | (dst << 16), r.y);
    }
}

// ---------------- layer 1: xs1 = X @ value1 (half-packed out) ----------------
__global__ __launch_bounds__(256) void k_value1(
        const float* __restrict__ X, const float* __restrict__ value1,
        const float* __restrict__ key1, const float* __restrict__ query1,
        const float* __restrict__ aw1,
        __half* __restrict__ xs1h, float* __restrict__ dotk1, float* __restrict__ dotq1) {
    __shared__ float W[INCH*C1];
    __shared__ float KV[C1], QV[C1];
    int tid = threadIdx.x;
    for (int i = tid; i < INCH*C1; i += 256) W[i] = value1[i];
    if (tid < C1) {
        float kv = 0.f, qv = 0.f;
#pragma unroll
        for (int j = 0; j < C1; ++j) {
            kv += key1[tid*C1+j]   * aw1[j];
            qv += query1[tid*C1+j] * aw1[C1+j];
        }
        KV[tid] = kv; QV[tid] = qv;
    }
    __syncthreads();
    int bn = blockIdx.x * 256 + tid;
    if (bn >= NB) return;
    int b = (bn >= NN) ? 1 : 0;
    int node = bn - b*NN;
    const float4* Xr = (const float4*)(X + (size_t)bn * INCH);
    float acc[C1];
#pragma unroll
    for (int j = 0; j < C1; ++j) acc[j] = 0.f;
#pragma unroll
    for (int v = 0; v < 16; ++v) {
        float4 p = Xr[v];
        float x4[4] = {p.x, p.y, p.z, p.w};
#pragma unroll
        for (int h = 0; h < 4; ++h) {
            int i = v*4 + h;
            float xv = x4[h];
#pragma unroll
            for (int j = 0; j < C1; ++j) acc[j] += xv * W[i*C1+j];
        }
    }
    float dk = 0.f, dq = 0.f;
#pragma unroll
    for (int j = 0; j < C1; ++j) { dk += acc[j]*KV[j]; dq += acc[j]*QV[j]; }
    __half* o = xs1h + ((size_t)node * C1) * 2 + b;
#pragma unroll
    for (int j = 0; j < C1; ++j) o[2*j] = __float2half_rn(acc[j]);
    dotk1[node*2 + b] = dk; dotq1[node*2 + b] = dq;
}

// ---------------- layer-1 message materialization: edge-parallel, loop-free --
__global__ __launch_bounds__(256) void k_gath1(
        const uint2* __restrict__ recs2, const float* __restrict__ we,
        const float* __restrict__ ab, const float* __restrict__ sc,
        const uint2* __restrict__ xsh, const float* __restrict__ dotk,
        const float* __restrict__ dotq, uint2* __restrict__ msg) {
    int t = blockIdx.x * 256 + threadIdx.x;      // grid exact: EE*8 threads
    int p = t >> 3, cp = t & 7;
    uint2 rec = recs2[p];
    int src = rec.x & 0xffff, dst = rec.x >> 16;
    float ef = __uint_as_float(rec.y);
    float se0 = sigmoidf(ef * we[2*cp]);
    float se1 = sigmoidf(ef * we[2*cp+1]);
    float eb  = ef * sc[0] + ab[0];
    float2 dq = *(const float2*)(dotq + src*2);
    float2 dk = *(const float2*)(dotk + dst*2);
    float a0 = sigmoidf(dk.x + dq.x + eb);
    float a1 = sigmoidf(dk.y + dq.y + eb);
    uint2 xr = xsh[(size_t)src*8 + cp];
    float2 f0 = __half22float2(__builtin_bit_cast(__half2, xr.x));
    float2 f1 = __half22float2(__builtin_bit_cast(__half2, xr.y));
    __half2 m0 = __floats2half2_rn(a0*se0*f0.x, a1*se0*f0.y);
    __half2 m1 = __floats2half2_rn(a0*se1*f1.x, a1*se1*f1.y);
    msg[(size_t)p*8 + cp] = make_uint2(__builtin_bit_cast(unsigned, m0),
                                       __builtin_bit_cast(unsigned, m1));
}

// ---------------- layer-1 segmented reduce: streaming, no gathers ------------
__global__ __launch_bounds__(256) void k_red1(
        const unsigned* __restrict__ startA, const unsigned* __restrict__ degA,
        const uint2* __restrict__ msg, float* __restrict__ aggrf) {
    int t = blockIdx.x * 256 + threadIdx.x;
    int node = t >> 3, cp = t & 7;
    if (node >= NN) return;
    unsigned s = startA[node];
    unsigned n = degA[node];
    float a0 = 0.f, a1 = 0.f, a2 = 0.f, a3 = 0.f;
    const uint2* mp = msg + (size_t)s*8 + cp;
    for (unsigned i = 0; i < n; ++i) {
        uint2 v = mp[(size_t)i*8];
        float2 f0 = __half22float2(__builtin_bit_cast(__half2, v.x));
        float2 f1 = __half22float2(__builtin_bit_cast(__half2, v.y));
        a0 += f0.x; a1 += f0.y; a2 += f1.x; a3 += f1.y;
    }
    ((float4*)aggrf)[(size_t)node*8 + cp] = make_float4(a0, a1, a2, a3);
}

// ---------------- fused: update1 + leaky_relu + xs2 = X1 @ value2 ------------
__global__ __launch_bounds__(256) void k_update1(
        const float* __restrict__ cat_w, const float* __restrict__ cat_b,
        const float* __restrict__ value2,
        const float* __restrict__ key2, const float* __restrict__ query2,
        const float* __restrict__ aw2,
        const __half* __restrict__ xs1h, const float* __restrict__ aggr1f,
        __half* __restrict__ xs2h, float* __restrict__ dotk2, float* __restrict__ dotq2) {
    __shared__ float CW[2*C1*C1];
    __shared__ float CB[C1];
    __shared__ float V2[C1*C2];
    __shared__ float KV[C2], QV[C2];
    int tid = threadIdx.x;
    for (int i = tid; i < 2*C1*C1; i += 256) CW[i] = cat_w[i];
    for (int i = tid; i < C1*C2;   i += 256) V2[i] = value2[i];
    if (tid < C1) CB[tid] = cat_b[tid];
    if (tid < C2) {
        float kv = 0.f;
#pragma unroll
        for (int j = 0; j < C2; ++j) kv += key2[tid*C2+j] * aw2[j];
        KV[tid] = kv;
    } else if (tid < 2*C2) {
        int c = tid - C2;
        float qv = 0.f;
#pragma unroll
        for (int j = 0; j < C2; ++j) qv += query2[c*C2+j] * aw2[C2+j];
        QV[c] = qv;
    }
    __syncthreads();
    int bn = blockIdx.x * 256 + tid;
    if (bn >= NB) return;
    int b = (bn >= NN) ? 1 : 0;
    int node = bn - b*NN;
    const __half* xr = xs1h + ((size_t)node*C1)*2 + b;
    const float* agp = aggr1f + (size_t)node*32;
    float xd[C1], ag[C1];
#pragma unroll
    for (int i = 0; i < C1; ++i) xd[i] = __half2float(xr[2*i]);
#pragma unroll
    for (int i = 0; i < C1; ++i) ag[i] = agp[(i>>1)*4 + (i&1)*2 + b];
    float x1[C1];
#pragma unroll
    for (int j = 0; j < C1; ++j) {
        float u = CB[j];
#pragma unroll
        for (int i = 0; i < C1; ++i) {
            u += xd[i] * CW[i*C1 + j];
            u += ag[i] * CW[(C1+i)*C1 + j];
        }
        float o = xd[j] + fmaxf(u, 0.f);
        x1[j] = (o > 0.f) ? o : 0.01f * o;       // leaky_relu
    }
    float o2[C2];
#pragma unroll
    for (int k = 0; k < C2; ++k) o2[k] = 0.f;
#pragma unroll
    for (int j = 0; j < C1; ++j) {
        float xv = x1[j];
#pragma unroll
        for (int k = 0; k < C2; ++k) o2[k] += xv * V2[j*C2 + k];
    }
    float dk = 0.f, dq = 0.f;
#pragma unroll
    for (int k = 0; k < C2; ++k) { dk += o2[k]*KV[k]; dq += o2[k]*QV[k]; }
    __half* o = xs2h + ((size_t)node*C2)*2 + b;
#pragma unroll
    for (int k = 0; k < C2; ++k) o[2*k] = __float2half_rn(o2[k]);
    dotk2[node*2 + b] = dk; dotq2[node*2 + b] = dq;
}

// ---------------- layer-2 message materialization: edge-parallel, loop-free --
__global__ __launch_bounds__(256) void k_gath2(
        const uint2* __restrict__ recs2, const float* __restrict__ we,
        const float* __restrict__ ab, const float* __restrict__ sc,
        const uint2* __restrict__ xsh, const float* __restrict__ dotk,
        const float* __restrict__ dotq, uint2* __restrict__ msg) {
    int t = blockIdx.x * 256 + threadIdx.x;      // grid exact: EE*16 threads
    int p = t >> 4, cp = t & 15;
    uint2 rec = recs2[EE + p];                   // layer-2 records live at [EE, 2EE)
    int src = rec.x & 0xffff, dst = rec.x >> 16;
    float ef = __uint_as_float(rec.y);
    float se0 = sigmoidf(ef * we[2*cp]);
    float se1 = sigmoidf(ef * we[2*cp+1]);
    float eb  = ef * sc[1] + ab[0];
    float2 dq = *(const float2*)(dotq + src*2);
    float2 dk = *(const float2*)(dotk + dst*2);
    float a0 = sigmoidf(dk.x + dq.x + eb);
    float a1 = sigmoidf(dk.y + dq.y + eb);
    uint2 xr = xsh[(size_t)src*16 + cp];
    float2 f0 = __half22float2(__builtin_bit_cast(__half2, xr.x));
    float2 f1 = __half22float2(__builtin_bit_cast(__half2, xr.y));
    __half2 m0 = __floats2half2_rn(a0*se0*f0.x, a1*se0*f0.y);
    __half2 m1 = __floats2half2_rn(a0*se1*f1.x, a1*se1*f1.y);
    msg[(size_t)p*16 + cp] = make_uint2(__builtin_bit_cast(unsigned, m0),
                                        __builtin_bit_cast(unsigned, m1));
}

// ---------------- layer-2 segmented reduce: streaming, no gathers ------------
__global__ __launch_bounds__(256) void k_red2(
        const unsigned* __restrict__ startA, const unsigned* __restrict__ degA,
        const uint2* __restrict__ msg, float* __restrict__ aggrf) {
    int t = blockIdx.x * 256 + threadIdx.x;
    int node = t >> 4, cp = t & 15;
    if (node >= NN) return;
    unsigned s = startA[NN + node] - EE;         // into layer-2 msg region
    unsigned n = degA[NN + node];
    float a0 = 0.f, a1 = 0.f, a2 = 0.f, a3 = 0.f;
    const uint2* mp = msg + (size_t)s*16 + cp;
    for (unsigned i = 0; i < n; ++i) {
        uint2 v = mp[(size_t)i*16];
        float2 f0 = __half22float2(__builtin_bit_cast(__half2, v.x));
        float2 f1 = __half22float2(__builtin_bit_cast(__half2, v.y));
        a0 += f0.x; a1 += f0.y; a2 += f1.x; a3 += f1.y;
    }
    ((float4*)aggrf)[(size_t)node*16 + cp] = make_float4(a0, a1, a2, a3);
}

// ---------------- final: update2 -> fp32 out [b][node][c] --------------------
__global__ __launch_bounds__(256) void k_update2(
        const float* __restrict__ cat_w, const float* __restrict__ cat_b,
        const __half* __restrict__ xs2h, const float* __restrict__ aggr2f,
        float* __restrict__ out) {
    __shared__ float CW[2*C2*C2];
    __shared__ float CB[C2];
    int tid = threadIdx.x;
    for (int i = tid; i < 2*C2*C2; i += 256) CW[i] = cat_w[i];
    if (tid < C2) CB[tid] = cat_b[tid];
    __syncthreads();
    int bn = blockIdx.x * 256 + tid;
    if (bn >= NB) return;
    int b = (bn >= NN) ? 1 : 0;
    int node = bn - b*NN;
    const __half* xr = xs2h + ((size_t)node*C2)*2 + b;
    const float* agp = aggr2f + (size_t)node*64;
    float xd[C2], ag[C2];
#pragma unroll
    for (int i = 0; i < C2; ++i) xd[i] = __half2float(xr[2*i]);
#pragma unroll
    for (int i = 0; i < C2; ++i) ag[i] = agp[(i>>1)*4 + (i&1)*2 + b];
    float o[C2];
#pragma unroll
    for (int k = 0; k < C2; ++k) {
        float u = CB[k];
#pragma unroll
        for (int i = 0; i < C2; ++i) {
            u += xd[i] * CW[i*C2 + k];
            u += ag[i] * CW[(C2+i)*C2 + k];
        }
        o[k] = xd[k] + fmaxf(u, 0.f);
    }
    float4* dst = (float4*)(out + (size_t)bn * C2);
#pragma unroll
    for (int v = 0; v < 8; ++v)
        dst[v] = make_float4(o[4*v], o[4*v+1], o[4*v+2], o[4*v+3]);
}

extern "C" void kernel_launch(void* const* d_in, const int* in_sizes, int n_in,
                              void* d_out, int out_size, void* d_ws, size_t ws_size,
                              hipStream_t stream) {
    const float* X      = (const float*)d_in[0];
    const int*   ei0    = (const int*)d_in[1];
    const int*   ei1    = (const int*)d_in[2];
    const float* ew0    = (const float*)d_in[3];
    const float* ew1    = (const float*)d_in[4];
    // d_in[5], d_in[6]: res_n_id0/1 == arange(N) -> identity gather, unused
    const float* value1 = (const float*)d_in[7];
    const float* key1   = (const float*)d_in[8];
    const float* query1 = (const float*)d_in[9];
    const float* we1    = (const float*)d_in[10];
    const float* aw1    = (const float*)d_in[11];
    const float* ab1    = (const float*)d_in[12];
    const float* cw1    = (const float*)d_in[13];
    const float* cb1    = (const float*)d_in[14];
    const float* value2 = (const float*)d_in[15];
    const float* key2   = (const float*)d_in[16];
    const float* query2 = (const float*)d_in[17];
    const float* we2    = (const float*)d_in[18];
    const float* aw2    = (const float*)d_in[19];
    const float* ab2    = (const float*)d_in[20];
    const float* cw2    = (const float*)d_in[21];
    const float* cb2    = (const float*)d_in[22];
    float* ws  = (float*)d_ws;
    float* out = (float*)d_out;

    __half* xs1h = (__half*)(ws + OFF_XS1);
    __half* xs2h = (__half*)(ws + OFF_XS2);
    float* aggr1f = ws + OFF_AG1;
    float* aggr2f = ws + OFF_AG2;
    unsigned* blockCnt   = (unsigned*)(ws + OFF_BCNT);
    unsigned* bktTot     = (unsigned*)(ws + OFF_BTOT);
    unsigned* bucketBase = (unsigned*)(ws + OFF_BBASE);
    unsigned* startA     = (unsigned*)(ws + OFF_START);
    unsigned* degA       = (unsigned*)(ws + OFF_DEG);
    uint2*    recs2      = (uint2*)(ws + OFF_RECS2);
    uint2*    recs       = (uint2*)(ws + OFF_RECS);
    uint2*    msg        = (uint2*)(ws + OFF_REGION);  // overlays recs+blockCnt (dead)

    k_sc<<<1, 64, 0, stream>>>(we1, aw1, we2, aw2, ws + OFF_SC);

    // node transform (independent of binning)
    k_value1<<<(NB+255)/256, 256, 0, stream>>>(X, value1, key1, query1, aw1,
                                               xs1h, ws + OFF_DOTK1, ws + OFF_DOTQ1);

    // deterministic two-level sort of both layers' edges by dst
    k_cnt<<<NEBLK, TPB, 0, stream>>>(ei0, ei1, blockCnt);
    k_scanBkt<<<NBKT, 512, 0, stream>>>(blockCnt, bktTot);
    k_scanTot<<<1, 1024, 0, stream>>>(bktTot, bucketBase);
    k_permute<<<NEBLK, TPB, 0, stream>>>(ei0, ei1, ew0, ew1,
                                         blockCnt, bucketBase, recs);
    k_sortb<<<NBKT, 256, 0, stream>>>(recs, bktTot, bucketBase,
                                      recs2, startA, degA);

    // layer 1: materialize messages edge-parallel, then streaming reduce
    k_gath1<<<(EE*8)/256, 256, 0, stream>>>(recs2, we1, ab1, ws + OFF_SC,
                                            (const uint2*)xs1h,
                                            ws + OFF_DOTK1, ws + OFF_DOTQ1, msg);
    k_red1<<<(NN*8+255)/256, 256, 0, stream>>>(startA, degA, msg, aggr1f);
    k_update1<<<(NB+255)/256, 256, 0, stream>>>(cw1, cb1, value2, key2, query2, aw2,
                                                xs1h, aggr1f,
                                                xs2h, ws + OFF_DOTK2, ws + OFF_DOTQ2);

    // layer 2
    k_gath2<<<(EE*16)/256, 256, 0, stream>>>(recs2, we2, ab2, ws + OFF_SC,
                                             (const uint2*)xs2h,
                                             ws + OFF_DOTK2, ws + OFF_DOTQ2, msg);
    k_red2<<<(NN*16+255)/256, 256, 0, stream>>>(startA, degA, msg, aggr2f);
    k_update2<<<(NB+255)/256, 256, 0, stream>>>(cw2, cb2, xs2h, aggr2f, out);
}

// Round 8
// 333.254 us; speedup vs baseline: 2.2927x; 1.0939x over previous
//
#include <hip/hip_runtime.h>
#include <hip/hip_fp16.h>

#define BB   2
#define NN   50000
#define EE   800000
#define INCH 64
#define C1   16
#define C2   32
#define NB   (BB*NN)

// radix binning geometry
#define W1S   6                      // layer-1 bucket = 64 dst nodes
#define W2S   5                      // layer-2 bucket = 32 dst nodes
#define NBK1  ((NN + 63) >> 6)       // 782
#define NBK2  ((NN + 31) >> 5)       // 1563
#define NBKT  (NBK1 + NBK2)          // 2345
#define EB    4096                   // edges per binning block
#define TPB   1024                   // threads per binning block
#define NEBLK ((2*EE + EB - 1) / EB) // 391

// workspace layout (float-unit offsets)
#define OFF_XS1   0                          // NB*C1 halves
#define OFF_XS2   (OFF_XS1 + NB*C1/2)        // NB*C2 halves
#define OFF_DOTK1 (OFF_XS2 + NB*C2/2)
#define OFF_DOTQ1 (OFF_DOTK1 + NB)
#define OFF_DOTK2 (OFF_DOTQ1 + NB)
#define OFF_DOTQ2 (OFF_DOTK2 + NB)
#define OFF_AG1   (OFF_DOTQ2 + NB)           // NN*32 floats
#define OFF_AG2   (OFF_AG1 + NN*32)          // NN*64 floats
#define OFF_BTOT  (OFF_AG2 + NN*64)          // NBKT u32
#define OFF_BBASE (OFF_BTOT + NBKT)          // NBKT u32
#define OFF_START (OFF_BBASE + NBKT)         // 2NN u32 (layer1 @ [0,NN), layer2 @ [NN,2NN))
#define OFF_DEG   (OFF_START + 2*NN)         // 2NN u32
#define OFF_SC    (OFF_DEG + 2*NN)           // 2 floats
#define OFF_RECS2 (OFF_SC + 2)               // 2*EE uint2 (dst-sorted records)
// alias region: recs (2*EE uint2) at its start, BCNT after recs; layer-1 msg
// (EE*8 uint2) overlays both once they are dead.
#define OFF_REGION (OFF_RECS2 + 2*EE*2)
#define OFF_RECS   OFF_REGION
#define OFF_BCNT   (OFF_REGION + 2*EE*2)

__device__ __forceinline__ float sigmoidf(float x) {
    return 1.0f / (1.0f + __expf(-x));
}

// ---------------- tiny scalar precompute -------------------------------------
__global__ void k_sc(const float* __restrict__ we1, const float* __restrict__ aw1,
                     const float* __restrict__ we2, const float* __restrict__ aw2,
                     float* __restrict__ sc) {
    if (threadIdx.x == 0) {
        float e = 0.f;
        for (int j = 0; j < C1; ++j) e += we1[j] * aw1[2*C1+j];
        sc[0] = e;
    }
    if (threadIdx.x == 1) {
        float e = 0.f;
        for (int j = 0; j < C2; ++j) e += we2[j] * aw2[2*C2+j];
        sc[1] = e;
    }
}

// ---------------- pass A: per-(block,bucket) histogram -----------------------
__global__ __launch_bounds__(TPB) void k_cnt(
        const int* __restrict__ ei0, const int* __restrict__ ei1,
        unsigned* __restrict__ blockCnt) {
    __shared__ unsigned h[NBKT];
    int tid = threadIdx.x;
    for (int i = tid; i < NBKT; i += TPB) h[i] = 0u;
    __syncthreads();
    int base = blockIdx.x * EB;
#pragma unroll
    for (int j = 0; j < EB/TPB; ++j) {
        int t = base + j*TPB + tid;
        if (t < 2*EE) {
            int bkt;
            if (t < EE) { int dst = ei0[EE + t];      bkt = dst >> W1S; }
            else        { int dst = ei1[EE + t - EE]; bkt = NBK1 + (dst >> W2S); }
            atomicAdd(&h[bkt], 1u);
        }
    }
    __syncthreads();
    unsigned* o = blockCnt + (size_t)blockIdx.x * NBKT;
    for (int i = tid; i < NBKT; i += TPB) o[i] = h[i];
}

// ---------------- pass B1: scan over blocks, per bucket (in-place) -----------
__global__ __launch_bounds__(512) void k_scanBkt(
        unsigned* __restrict__ blockCnt, unsigned* __restrict__ bktTot) {
    __shared__ unsigned s[512];
    int tid = threadIdx.x;
    int bkt = blockIdx.x;
    unsigned v = (tid < NEBLK) ? blockCnt[(size_t)tid * NBKT + bkt] : 0u;
    s[tid] = v;
    __syncthreads();
    for (int o = 1; o < 512; o <<= 1) {
        unsigned t = (tid >= o) ? s[tid - o] : 0u;
        __syncthreads();
        s[tid] += t;
        __syncthreads();
    }
    if (tid < NEBLK) blockCnt[(size_t)tid * NBKT + bkt] = s[tid] - v;  // exclusive
    if (tid == 511) bktTot[bkt] = s[511];
}

// ---------------- pass B2: scan bucket totals -> bucket bases ----------------
__global__ __launch_bounds__(1024) void k_scanTot(
        const unsigned* __restrict__ bktTot, unsigned* __restrict__ bucketBase) {
    __shared__ unsigned s[1024];
    int tid = threadIdx.x;
    int base = tid * 3;
    unsigned a0 = (base + 0 < NBKT) ? bktTot[base + 0] : 0u;
    unsigned a1 = (base + 1 < NBKT) ? bktTot[base + 1] : 0u;
    unsigned a2 = (base + 2 < NBKT) ? bktTot[base + 2] : 0u;
    unsigned l = a0 + a1 + a2;
    s[tid] = l;
    __syncthreads();
    for (int o = 1; o < 1024; o <<= 1) {
        unsigned t = (tid >= o) ? s[tid - o] : 0u;
        __syncthreads();
        s[tid] += t;
        __syncthreads();
    }
    unsigned ex = s[tid] - l;
    if (base + 0 < NBKT) bucketBase[base + 0] = ex;
    if (base + 1 < NBKT) bucketBase[base + 1] = ex + a0;
    if (base + 2 < NBKT) bucketBase[base + 2] = ex + a0 + a1;
}

// ---------------- pass C: permute edge records into bucket-grouped order -----
__global__ __launch_bounds__(TPB) void k_permute(
        const int* __restrict__ ei0, const int* __restrict__ ei1,
        const float* __restrict__ ew0, const float* __restrict__ ew1,
        const unsigned* __restrict__ blockOff, const unsigned* __restrict__ bucketBase,
        uint2* __restrict__ recs) {
    __shared__ unsigned off[NBKT];
    __shared__ unsigned cur[NBKT];
    int tid = threadIdx.x;
    const unsigned* bo = blockOff + (size_t)blockIdx.x * NBKT;
    for (int i = tid; i < NBKT; i += TPB) { off[i] = bo[i] + bucketBase[i]; cur[i] = 0u; }
    __syncthreads();
    int base = blockIdx.x * EB;
#pragma unroll
    for (int j = 0; j < EB/TPB; ++j) {
        int t = base + j*TPB + tid;
        if (t >= 2*EE) break;
        int bkt, dl, src; float ef;
        if (t < EE) {
            int dst = ei0[EE + t];
            bkt = dst >> W1S; dl = dst & 63;
            src = ei0[t]; ef = ew0[t];
        } else {
            int e = t - EE;
            int dst = ei1[EE + e];
            bkt = NBK1 + (dst >> W2S); dl = dst & 31;
            src = ei1[e]; ef = ew1[e];
        }
        unsigned pos = off[bkt] + atomicAdd(&cur[bkt], 1u);
        recs[pos] = make_uint2((unsigned)src | ((unsigned)dl << 16), __float_as_uint(ef));
    }
}

// ---------------- pass D: per-bucket counting sort by dst -> exact CSR -------
__global__ __launch_bounds__(256) void k_sortb(
        const uint2* __restrict__ recs, const unsigned* __restrict__ bktTot,
        const unsigned* __restrict__ bucketBase,
        uint2* __restrict__ recs2, unsigned* __restrict__ startA,
        unsigned* __restrict__ degA) {
    __shared__ unsigned h[64], sOff[64], cur[64];
    int tid = threadIdx.x;
    int bkt = blockIdx.x;
    int lay1 = (bkt < NBK1) ? 1 : 0;
    int ndl  = lay1 ? 64 : 32;
    int nodeBase = lay1 ? (bkt << W1S) : ((bkt - NBK1) << W2S);
    int layOff   = lay1 ? 0 : NN;
    if (tid < 64) h[tid] = 0u;
    __syncthreads();
    unsigned cnt = bktTot[bkt], base = bucketBase[bkt];
    for (unsigned i = tid; i < cnt; i += 256)
        atomicAdd(&h[recs[base + i].x >> 16], 1u);
    __syncthreads();
    if (tid == 0) {
        unsigned run = 0;
        for (int d = 0; d < ndl; ++d) { sOff[d] = run; run += h[d]; }
    }
    __syncthreads();
    if (tid < ndl) {
        cur[tid] = sOff[tid];
        int node = nodeBase + tid;
        if (node < NN) {
            startA[layOff + node] = base + sOff[tid];
            degA[layOff + node]   = h[tid];
        }
    }
    __syncthreads();
    for (unsigned i = tid; i < cnt; i += 256) {
        uint2 r = recs[base + i];
        unsigned dl  = r.x >> 16;
        unsigned src = r.x & 0xffffu;
        unsigned pos = atomicAdd(&cur[dl], 1u);
        unsigned dst = (unsigned)nodeBase + dl;
        recs2[base + pos] = make_uint2(src | (dst << 16), r.y);
    }
}

// ---------------- layer 1: xs1 = X @ value1 (half-packed out) ----------------
__global__ __launch_bounds__(256) void k_value1(
        const float* __restrict__ X, const float* __restrict__ value1,
        const float* __restrict__ key1, const float* __restrict__ query1,
        const float* __restrict__ aw1,
        __half* __restrict__ xs1h, float* __restrict__ dotk1, float* __restrict__ dotq1) {
    __shared__ float W[INCH*C1];
    __shared__ float KV[C1], QV[C1];
    int tid = threadIdx.x;
    for (int i = tid; i < INCH*C1; i += 256) W[i] = value1[i];
    if (tid < C1) {
        float kv = 0.f, qv = 0.f;
#pragma unroll
        for (int j = 0; j < C1; ++j) {
            kv += key1[tid*C1+j]   * aw1[j];
            qv += query1[tid*C1+j] * aw1[C1+j];
        }
        KV[tid] = kv; QV[tid] = qv;
    }
    __syncthreads();
    int bn = blockIdx.x * 256 + tid;
    if (bn >= NB) return;
    int b = (bn >= NN) ? 1 : 0;
    int node = bn - b*NN;
    const float4* Xr = (const float4*)(X + (size_t)bn * INCH);
    float acc[C1];
#pragma unroll
    for (int j = 0; j < C1; ++j) acc[j] = 0.f;
#pragma unroll
    for (int v = 0; v < 16; ++v) {
        float4 p = Xr[v];
        float x4[4] = {p.x, p.y, p.z, p.w};
#pragma unroll
        for (int h = 0; h < 4; ++h) {
            int i = v*4 + h;
            float xv = x4[h];
#pragma unroll
            for (int j = 0; j < C1; ++j) acc[j] += xv * W[i*C1+j];
        }
    }
    float dk = 0.f, dq = 0.f;
#pragma unroll
    for (int j = 0; j < C1; ++j) { dk += acc[j]*KV[j]; dq += acc[j]*QV[j]; }
    __half* o = xs1h + ((size_t)node * C1) * 2 + b;
#pragma unroll
    for (int j = 0; j < C1; ++j) o[2*j] = __float2half_rn(acc[j]);
    dotk1[node*2 + b] = dk; dotq1[node*2 + b] = dq;
}

// ---------------- layer-1 message materialization: edge-parallel, loop-free --
__global__ __launch_bounds__(256) void k_gath1(
        const uint2* __restrict__ recs2, const float* __restrict__ we,
        const float* __restrict__ ab, const float* __restrict__ sc,
        const uint2* __restrict__ xsh, const float* __restrict__ dotk,
        const float* __restrict__ dotq, uint2* __restrict__ msg) {
    int t = blockIdx.x * 256 + threadIdx.x;      // grid exact: EE*8 threads
    int p = t >> 3, cp = t & 7;
    uint2 rec = recs2[p];
    int src = rec.x & 0xffff, dst = rec.x >> 16;
    float ef = __uint_as_float(rec.y);
    float se0 = sigmoidf(ef * we[2*cp]);
    float se1 = sigmoidf(ef * we[2*cp+1]);
    float eb  = ef * sc[0] + ab[0];
    float2 dq = *(const float2*)(dotq + src*2);
    float2 dk = *(const float2*)(dotk + dst*2);
    float a0 = sigmoidf(dk.x + dq.x + eb);
    float a1 = sigmoidf(dk.y + dq.y + eb);
    uint2 xr = xsh[(size_t)src*8 + cp];
    float2 f0 = __half22float2(__builtin_bit_cast(__half2, xr.x));
    float2 f1 = __half22float2(__builtin_bit_cast(__half2, xr.y));
    __half2 m0 = __floats2half2_rn(a0*se0*f0.x, a1*se0*f0.y);
    __half2 m1 = __floats2half2_rn(a0*se1*f1.x, a1*se1*f1.y);
    msg[(size_t)p*8 + cp] = make_uint2(__builtin_bit_cast(unsigned, m0),
                                       __builtin_bit_cast(unsigned, m1));
}

// ---------------- layer-1 segmented reduce: streaming, no gathers ------------
__global__ __launch_bounds__(256) void k_red1(
        const unsigned* __restrict__ startA, const unsigned* __restrict__ degA,
        const uint2* __restrict__ msg, float* __restrict__ aggrf) {
    int t = blockIdx.x * 256 + threadIdx.x;
    int node = t >> 3, cp = t & 7;
    if (node >= NN) return;
    unsigned s = startA[node];
    unsigned n = degA[node];
    float a0 = 0.f, a1 = 0.f, a2 = 0.f, a3 = 0.f;
    const uint2* mp = msg + (size_t)s*8 + cp;
    for (unsigned i = 0; i < n; ++i) {
        uint2 v = mp[(size_t)i*8];
        float2 f0 = __half22float2(__builtin_bit_cast(__half2, v.x));
        float2 f1 = __half22float2(__builtin_bit_cast(__half2, v.y));
        a0 += f0.x; a1 += f0.y; a2 += f1.x; a3 += f1.y;
    }
    ((float4*)aggrf)[(size_t)node*8 + cp] = make_float4(a0, a1, a2, a3);
}

// ---------------- fused: update1 + leaky_relu + xs2 = X1 @ value2 ------------
__global__ __launch_bounds__(256) void k_update1(
        const float* __restrict__ cat_w, const float* __restrict__ cat_b,
        const float* __restrict__ value2,
        const float* __restrict__ key2, const float* __restrict__ query2,
        const float* __restrict__ aw2,
        const __half* __restrict__ xs1h, const float* __restrict__ aggr1f,
        __half* __restrict__ xs2h, float* __restrict__ dotk2, float* __restrict__ dotq2) {
    __shared__ float CW[2*C1*C1];
    __shared__ float CB[C1];
    __shared__ float V2[C1*C2];
    __shared__ float KV[C2], QV[C2];
    int tid = threadIdx.x;
    for (int i = tid; i < 2*C1*C1; i += 256) CW[i] = cat_w[i];
    for (int i = tid; i < C1*C2;   i += 256) V2[i] = value2[i];
    if (tid < C1) CB[tid] = cat_b[tid];
    if (tid < C2) {
        float kv = 0.f;
#pragma unroll
        for (int j = 0; j < C2; ++j) kv += key2[tid*C2+j] * aw2[j];
        KV[tid] = kv;
    } else if (tid < 2*C2) {
        int c = tid - C2;
        float qv = 0.f;
#pragma unroll
        for (int j = 0; j < C2; ++j) qv += query2[c*C2+j] * aw2[C2+j];
        QV[c] = qv;
    }
    __syncthreads();
    int bn = blockIdx.x * 256 + tid;
    if (bn >= NB) return;
    int b = (bn >= NN) ? 1 : 0;
    int node = bn - b*NN;
    const __half* xr = xs1h + ((size_t)node*C1)*2 + b;
    const float* agp = aggr1f + (size_t)node*32;
    float xd[C1], ag[C1];
#pragma unroll
    for (int i = 0; i < C1; ++i) xd[i] = __half2float(xr[2*i]);
#pragma unroll
    for (int i = 0; i < C1; ++i) ag[i] = agp[(i>>1)*4 + (i&1)*2 + b];
    float x1[C1];
#pragma unroll
    for (int j = 0; j < C1; ++j) {
        float u = CB[j];
#pragma unroll
        for (int i = 0; i < C1; ++i) {
            u += xd[i] * CW[i*C1 + j];
            u += ag[i] * CW[(C1+i)*C1 + j];
        }
        float o = xd[j] + fmaxf(u, 0.f);
        x1[j] = (o > 0.f) ? o : 0.01f * o;       // leaky_relu
    }
    float o2[C2];
#pragma unroll
    for (int k = 0; k < C2; ++k) o2[k] = 0.f;
#pragma unroll
    for (int j = 0; j < C1; ++j) {
        float xv = x1[j];
#pragma unroll
        for (int k = 0; k < C2; ++k) o2[k] += xv * V2[j*C2 + k];
    }
    float dk = 0.f, dq = 0.f;
#pragma unroll
    for (int k = 0; k < C2; ++k) { dk += o2[k]*KV[k]; dq += o2[k]*QV[k]; }
    __half* o = xs2h + ((size_t)node*C2)*2 + b;
#pragma unroll
    for (int k = 0; k < C2; ++k) o[2*k] = __float2half_rn(o2[k]);
    dotk2[node*2 + b] = dk; dotq2[node*2 + b] = dq;
}

// ---------------- layer-2 FUSED gather+reduce: per-(node,cp), pipelined ------
// Experiment: replaces gath2 (102 MB msg write) + red2 (102 MB msg read).
// Records are dst-sorted so rec reads are contiguous per node (L2 broadcast
// across the 16 cp lanes); only xsh/dotq reads are gathers.
__global__ __launch_bounds__(256) void k_aggr2f(
        const uint2* __restrict__ recs2, const float* __restrict__ we,
        const float* __restrict__ ab, const float* __restrict__ sc,
        const uint2* __restrict__ xsh, const float* __restrict__ dotk,
        const float* __restrict__ dotq,
        const unsigned* __restrict__ startA, const unsigned* __restrict__ degA,
        float* __restrict__ aggrf) {
    int t = blockIdx.x * 256 + threadIdx.x;
    int node = t >> 4, cp = t & 15;
    if (node >= NN) return;
    unsigned s = startA[NN + node];              // absolute into recs2
    unsigned n = degA[NN + node];
    float w0 = we[2*cp], w1 = we[2*cp+1];
    float ec = sc[1], bias = ab[0];
    float2 dk = *(const float2*)(dotk + node*2);
    float a0 = 0.f, a1 = 0.f, a2 = 0.f, a3 = 0.f;
    // 1-deep software pipeline: next record's rec + gathers in flight
    int src_n = 0; float ef_n = 0.f; float2 dq_n = make_float2(0.f, 0.f);
    uint2 xr_n = make_uint2(0u, 0u);
    if (n > 0) {
        uint2 r = recs2[s];
        src_n = r.x & 0xffff; ef_n = __uint_as_float(r.y);
        dq_n = *(const float2*)(dotq + src_n*2);
        xr_n = xsh[(size_t)src_n*16 + cp];
    }
    for (unsigned i = 0; i < n; ++i) {
        float ef = ef_n; float2 dq = dq_n; uint2 xr = xr_n;
        if (i + 1 < n) {
            uint2 r = recs2[s + i + 1];
            src_n = r.x & 0xffff; ef_n = __uint_as_float(r.y);
            dq_n = *(const float2*)(dotq + src_n*2);
            xr_n = xsh[(size_t)src_n*16 + cp];
        }
        float se0 = sigmoidf(ef * w0);
        float se1 = sigmoidf(ef * w1);
        float eb  = ef * ec + bias;
        float p0 = sigmoidf(dk.x + dq.x + eb);
        float p1 = sigmoidf(dk.y + dq.y + eb);
        float2 f0 = __half22float2(__builtin_bit_cast(__half2, xr.x));
        float2 f1 = __half22float2(__builtin_bit_cast(__half2, xr.y));
        a0 += p0 * se0 * f0.x;
        a1 += p1 * se0 * f0.y;
        a2 += p0 * se1 * f1.x;
        a3 += p1 * se1 * f1.y;
    }
    ((float4*)aggrf)[(size_t)node*16 + cp] = make_float4(a0, a1, a2, a3);
}

// ---------------- final: update2 -> fp32 out [b][node][c] --------------------
__global__ __launch_bounds__(256) void k_update2(
        const float* __restrict__ cat_w, const float* __restrict__ cat_b,
        const __half* __restrict__ xs2h, const float* __restrict__ aggr2f,
        float* __restrict__ out) {
    __shared__ float CW[2*C2*C2];
    __shared__ float CB[C2];
    int tid = threadIdx.x;
    for (int i = tid; i < 2*C2*C2; i += 256) CW[i] = cat_w[i];
    if (tid < C2) CB[tid] = cat_b[tid];
    __syncthreads();
    int bn = blockIdx.x * 256 + tid;
    if (bn >= NB) return;
    int b = (bn >= NN) ? 1 : 0;
    int node = bn - b*NN;
    const __half* xr = xs2h + ((size_t)node*C2)*2 + b;
    const float* agp = aggr2f + (size_t)node*64;
    float xd[C2], ag[C2];
#pragma unroll
    for (int i = 0; i < C2; ++i) xd[i] = __half2float(xr[2*i]);
#pragma unroll
    for (int i = 0; i < C2; ++i) ag[i] = agp[(i>>1)*4 + (i&1)*2 + b];
    float o[C2];
#pragma unroll
    for (int k = 0; k < C2; ++k) {
        float u = CB[k];
#pragma unroll
        for (int i = 0; i < C2; ++i) {
            u += xd[i] * CW[i*C2 + k];
            u += ag[i] * CW[(C2+i)*C2 + k];
        }
        o[k] = xd[k] + fmaxf(u, 0.f);
    }
    float4* dst = (float4*)(out + (size_t)bn * C2);
#pragma unroll
    for (int v = 0; v < 8; ++v)
        dst[v] = make_float4(o[4*v], o[4*v+1], o[4*v+2], o[4*v+3]);
}

extern "C" void kernel_launch(void* const* d_in, const int* in_sizes, int n_in,
                              void* d_out, int out_size, void* d_ws, size_t ws_size,
                              hipStream_t stream) {
    const float* X      = (const float*)d_in[0];
    const int*   ei0    = (const int*)d_in[1];
    const int*   ei1    = (const int*)d_in[2];
    const float* ew0    = (const float*)d_in[3];
    const float* ew1    = (const float*)d_in[4];
    // d_in[5], d_in[6]: res_n_id0/1 == arange(N) -> identity gather, unused
    const float* value1 = (const float*)d_in[7];
    const float* key1   = (const float*)d_in[8];
    const float* query1 = (const float*)d_in[9];
    const float* we1    = (const float*)d_in[10];
    const float* aw1    = (const float*)d_in[11];
    const float* ab1    = (const float*)d_in[12];
    const float* cw1    = (const float*)d_in[13];
    const float* cb1    = (const float*)d_in[14];
    const float* value2 = (const float*)d_in[15];
    const float* key2   = (const float*)d_in[16];
    const float* query2 = (const float*)d_in[17];
    const float* we2    = (const float*)d_in[18];
    const float* aw2    = (const float*)d_in[19];
    const float* ab2    = (const float*)d_in[20];
    const float* cw2    = (const float*)d_in[21];
    const float* cb2    = (const float*)d_in[22];
    float* ws  = (float*)d_ws;
    float* out = (float*)d_out;

    __half* xs1h = (__half*)(ws + OFF_XS1);
    __half* xs2h = (__half*)(ws + OFF_XS2);
    float* aggr1f = ws + OFF_AG1;
    float* aggr2f = ws + OFF_AG2;
    unsigned* blockCnt   = (unsigned*)(ws + OFF_BCNT);
    unsigned* bktTot     = (unsigned*)(ws + OFF_BTOT);
    unsigned* bucketBase = (unsigned*)(ws + OFF_BBASE);
    unsigned* startA     = (unsigned*)(ws + OFF_START);
    unsigned* degA       = (unsigned*)(ws + OFF_DEG);
    uint2*    recs2      = (uint2*)(ws + OFF_RECS2);
    uint2*    recs       = (uint2*)(ws + OFF_RECS);
    uint2*    msg        = (uint2*)(ws + OFF_REGION);  // overlays recs+blockCnt (dead)

    k_sc<<<1, 64, 0, stream>>>(we1, aw1, we2, aw2, ws + OFF_SC);

    // node transform (independent of binning)
    k_value1<<<(NB+255)/256, 256, 0, stream>>>(X, value1, key1, query1, aw1,
                                               xs1h, ws + OFF_DOTK1, ws + OFF_DOTQ1);

    // deterministic two-level sort of both layers' edges by dst
    k_cnt<<<NEBLK, TPB, 0, stream>>>(ei0, ei1, blockCnt);
    k_scanBkt<<<NBKT, 512, 0, stream>>>(blockCnt, bktTot);
    k_scanTot<<<1, 1024, 0, stream>>>(bktTot, bucketBase);
    k_permute<<<NEBLK, TPB, 0, stream>>>(ei0, ei1, ew0, ew1,
                                         blockCnt, bucketBase, recs);
    k_sortb<<<NBKT, 256, 0, stream>>>(recs, bktTot, bucketBase,
                                      recs2, startA, degA);

    // layer 1: materialize messages edge-parallel, then streaming reduce
    k_gath1<<<(EE*8)/256, 256, 0, stream>>>(recs2, we1, ab1, ws + OFF_SC,
                                            (const uint2*)xs1h,
                                            ws + OFF_DOTK1, ws + OFF_DOTQ1, msg);
    k_red1<<<(NN*8+255)/256, 256, 0, stream>>>(startA, degA, msg, aggr1f);
    k_update1<<<(NB+255)/256, 256, 0, stream>>>(cw1, cb1, value2, key2, query2, aw2,
                                                xs1h, aggr1f,
                                                xs2h, ws + OFF_DOTK2, ws + OFF_DOTQ2);

    // layer 2: fused gather+reduce (experiment vs layer-1 control)
    k_aggr2f<<<(NN*16+255)/256, 256, 0, stream>>>(recs2, we2, ab2, ws + OFF_SC,
                                                  (const uint2*)xs2h,
                                                  ws + OFF_DOTK2, ws + OFF_DOTQ2,
                                                  startA, degA, aggr2f);
    k_update2<<<(NB+255)/256, 256, 0, stream>>>(cw2, cb2, xs2h, aggr2f, out);
}

// Round 9
// 327.383 us; speedup vs baseline: 2.3338x; 1.0179x over previous
//
#include <hip/hip_runtime.h>
#include <hip/hip_fp16.h>

#define BB   2
#define NN   50000
#define EE   800000
#define INCH 64
#define C1   16
#define C2   32
#define NB   (BB*NN)

// radix binning geometry
#define W1S   6                      // layer-1 bucket = 64 dst nodes
#define W2S   5                      // layer-2 bucket = 32 dst nodes
#define NBK1  ((NN + 63) >> 6)       // 782
#define NBK2  ((NN + 31) >> 5)       // 1563
#define NBKT  (NBK1 + NBK2)          // 2345
#define EB    4096                   // edges per binning block
#define TPB   1024                   // threads per binning block
#define NEBLK ((2*EE + EB - 1) / EB) // 391

// workspace layout (float-unit offsets)
#define OFF_XS1   0                          // NB*C1 halves
#define OFF_XS2   (OFF_XS1 + NB*C1/2)        // NB*C2 halves
#define OFF_DOTK1 (OFF_XS2 + NB*C2/2)
#define OFF_DOTQ1 (OFF_DOTK1 + NB)
#define OFF_DOTK2 (OFF_DOTQ1 + NB)
#define OFF_DOTQ2 (OFF_DOTK2 + NB)
#define OFF_AG1   (OFF_DOTQ2 + NB)           // NN*32 floats
#define OFF_AG2   (OFF_AG1 + NN*32)          // NN*64 floats
#define OFF_BTOT  (OFF_AG2 + NN*64)          // NBKT u32
#define OFF_BBASE (OFF_BTOT + NBKT)          // NBKT u32
#define OFF_START (OFF_BBASE + NBKT)         // 2NN u32 (layer1 @ [0,NN), layer2 @ [NN,2NN))
#define OFF_DEG   (OFF_START + 2*NN)         // 2NN u32
#define OFF_SC    (OFF_DEG + 2*NN)           // 2 floats
#define OFF_RECS2 (OFF_SC + 2)               // 2*EE uint2 (dst-sorted records)
// alias region: recs (2*EE uint2) at its start, BCNT after recs; per-edge
// attention-precompute buffer prec (EE uint2) overlays recs once it is dead.
#define OFF_REGION (OFF_RECS2 + 2*EE*2)
#define OFF_RECS   OFF_REGION
#define OFF_BCNT   (OFF_REGION + 2*EE*2)
#define OFF_PREC   OFF_REGION

__device__ __forceinline__ float sigmoidf(float x) {
    // v_exp + v_rcp, no IEEE-div Newton steps (tolerance is loose)
    return __builtin_amdgcn_rcpf(1.0f + __expf(-x));
}

// ---------------- tiny scalar precompute -------------------------------------
__global__ void k_sc(const float* __restrict__ we1, const float* __restrict__ aw1,
                     const float* __restrict__ we2, const float* __restrict__ aw2,
                     float* __restrict__ sc) {
    if (threadIdx.x == 0) {
        float e = 0.f;
        for (int j = 0; j < C1; ++j) e += we1[j] * aw1[2*C1+j];
        sc[0] = e;
    }
    if (threadIdx.x == 1) {
        float e = 0.f;
        for (int j = 0; j < C2; ++j) e += we2[j] * aw2[2*C2+j];
        sc[1] = e;
    }
}

// ---------------- pass A: per-(block,bucket) histogram -----------------------
__global__ __launch_bounds__(TPB) void k_cnt(
        const int* __restrict__ ei0, const int* __restrict__ ei1,
        unsigned* __restrict__ blockCnt) {
    __shared__ unsigned h[NBKT];
    int tid = threadIdx.x;
    for (int i = tid; i < NBKT; i += TPB) h[i] = 0u;
    __syncthreads();
    int base = blockIdx.x * EB;
#pragma unroll
    for (int j = 0; j < EB/TPB; ++j) {
        int t = base + j*TPB + tid;
        if (t < 2*EE) {
            int bkt;
            if (t < EE) { int dst = ei0[EE + t];      bkt = dst >> W1S; }
            else        { int dst = ei1[EE + t - EE]; bkt = NBK1 + (dst >> W2S); }
            atomicAdd(&h[bkt], 1u);
        }
    }
    __syncthreads();
    unsigned* o = blockCnt + (size_t)blockIdx.x * NBKT;
    for (int i = tid; i < NBKT; i += TPB) o[i] = h[i];
}

// ---------------- pass B1: scan over blocks, per bucket (in-place) -----------
__global__ __launch_bounds__(512) void k_scanBkt(
        unsigned* __restrict__ blockCnt, unsigned* __restrict__ bktTot) {
    __shared__ unsigned s[512];
    int tid = threadIdx.x;
    int bkt = blockIdx.x;
    unsigned v = (tid < NEBLK) ? blockCnt[(size_t)tid * NBKT + bkt] : 0u;
    s[tid] = v;
    __syncthreads();
    for (int o = 1; o < 512; o <<= 1) {
        unsigned t = (tid >= o) ? s[tid - o] : 0u;
        __syncthreads();
        s[tid] += t;
        __syncthreads();
    }
    if (tid < NEBLK) blockCnt[(size_t)tid * NBKT + bkt] = s[tid] - v;  // exclusive
    if (tid == 511) bktTot[bkt] = s[511];
}

// ---------------- pass B2: scan bucket totals -> bucket bases ----------------
__global__ __launch_bounds__(1024) void k_scanTot(
        const unsigned* __restrict__ bktTot, unsigned* __restrict__ bucketBase) {
    __shared__ unsigned s[1024];
    int tid = threadIdx.x;
    int base = tid * 3;
    unsigned a0 = (base + 0 < NBKT) ? bktTot[base + 0] : 0u;
    unsigned a1 = (base + 1 < NBKT) ? bktTot[base + 1] : 0u;
    unsigned a2 = (base + 2 < NBKT) ? bktTot[base + 2] : 0u;
    unsigned l = a0 + a1 + a2;
    s[tid] = l;
    __syncthreads();
    for (int o = 1; o < 1024; o <<= 1) {
        unsigned t = (tid >= o) ? s[tid - o] : 0u;
        __syncthreads();
        s[tid] += t;
        __syncthreads();
    }
    unsigned ex = s[tid] - l;
    if (base + 0 < NBKT) bucketBase[base + 0] = ex;
    if (base + 1 < NBKT) bucketBase[base + 1] = ex + a0;
    if (base + 2 < NBKT) bucketBase[base + 2] = ex + a0 + a1;
}

// ---------------- pass C: permute edge records into bucket-grouped order -----
__global__ __launch_bounds__(TPB) void k_permute(
        const int* __restrict__ ei0, const int* __restrict__ ei1,
        const float* __restrict__ ew0, const float* __restrict__ ew1,
        const unsigned* __restrict__ blockOff, const unsigned* __restrict__ bucketBase,
        uint2* __restrict__ recs) {
    __shared__ unsigned off[NBKT];
    __shared__ unsigned cur[NBKT];
    int tid = threadIdx.x;
    const unsigned* bo = blockOff + (size_t)blockIdx.x * NBKT;
    for (int i = tid; i < NBKT; i += TPB) { off[i] = bo[i] + bucketBase[i]; cur[i] = 0u; }
    __syncthreads();
    int base = blockIdx.x * EB;
#pragma unroll
    for (int j = 0; j < EB/TPB; ++j) {
        int t = base + j*TPB + tid;
        if (t >= 2*EE) break;
        int bkt, dl, src; float ef;
        if (t < EE) {
            int dst = ei0[EE + t];
            bkt = dst >> W1S; dl = dst & 63;
            src = ei0[t]; ef = ew0[t];
        } else {
            int e = t - EE;
            int dst = ei1[EE + e];
            bkt = NBK1 + (dst >> W2S); dl = dst & 31;
            src = ei1[e]; ef = ew1[e];
        }
        unsigned pos = off[bkt] + atomicAdd(&cur[bkt], 1u);
        recs[pos] = make_uint2((unsigned)src | ((unsigned)dl << 16), __float_as_uint(ef));
    }
}

// ---------------- pass D: per-bucket counting sort by dst -> exact CSR -------
__global__ __launch_bounds__(256) void k_sortb(
        const uint2* __restrict__ recs, const unsigned* __restrict__ bktTot,
        const unsigned* __restrict__ bucketBase,
        uint2* __restrict__ recs2, unsigned* __restrict__ startA,
        unsigned* __restrict__ degA) {
    __shared__ unsigned h[64], sOff[64], cur[64];
    int tid = threadIdx.x;
    int bkt = blockIdx.x;
    int lay1 = (bkt < NBK1) ? 1 : 0;
    int ndl  = lay1 ? 64 : 32;
    int nodeBase = lay1 ? (bkt << W1S) : ((bkt - NBK1) << W2S);
    int layOff   = lay1 ? 0 : NN;
    if (tid < 64) h[tid] = 0u;
    __syncthreads();
    unsigned cnt = bktTot[bkt], base = bucketBase[bkt];
    for (unsigned i = tid; i < cnt; i += 256)
        atomicAdd(&h[recs[base + i].x >> 16], 1u);
    __syncthreads();
    if (tid == 0) {
        unsigned run = 0;
        for (int d = 0; d < ndl; ++d) { sOff[d] = run; run += h[d]; }
    }
    __syncthreads();
    if (tid < ndl) {
        cur[tid] = sOff[tid];
        int node = nodeBase + tid;
        if (node < NN) {
            startA[layOff + node] = base + sOff[tid];
            degA[layOff + node]   = h[tid];
        }
    }
    __syncthreads();
    for (unsigned i = tid; i < cnt; i += 256) {
        uint2 r = recs[base + i];
        unsigned dl  = r.x >> 16;
        unsigned src = r.x & 0xffffu;
        unsigned pos = atomicAdd(&cur[dl], 1u);
        unsigned dst = (unsigned)nodeBase + dl;
        recs2[base + pos] = make_uint2(src | (dst << 16), r.y);
    }
}

// ---------------- layer 1: xs1 = X @ value1 (half-packed out) ----------------
__global__ __launch_bounds__(256) void k_value1(
        const float* __restrict__ X, const float* __restrict__ value1,
        const float* __restrict__ key1, const float* __restrict__ query1,
        const float* __restrict__ aw1,
        __half* __restrict__ xs1h, float* __restrict__ dotk1, float* __restrict__ dotq1) {
    __shared__ float W[INCH*C1];
    __shared__ float KV[C1], QV[C1];
    int tid = threadIdx.x;
    for (int i = tid; i < INCH*C1; i += 256) W[i] = value1[i];
    if (tid < C1) {
        float kv = 0.f, qv = 0.f;
#pragma unroll
        for (int j = 0; j < C1; ++j) {
            kv += key1[tid*C1+j]   * aw1[j];
            qv += query1[tid*C1+j] * aw1[C1+j];
        }
        KV[tid] = kv; QV[tid] = qv;
    }
    __syncthreads();
    int bn = blockIdx.x * 256 + tid;
    if (bn >= NB) return;
    int b = (bn >= NN) ? 1 : 0;
    int node = bn - b*NN;
    const float4* Xr = (const float4*)(X + (size_t)bn * INCH);
    float acc[C1];
#pragma unroll
    for (int j = 0; j < C1; ++j) acc[j] = 0.f;
#pragma unroll
    for (int v = 0; v < 16; ++v) {
        float4 p = Xr[v];
        float x4[4] = {p.x, p.y, p.z, p.w};
#pragma unroll
        for (int h = 0; h < 4; ++h) {
            int i = v*4 + h;
            float xv = x4[h];
#pragma unroll
            for (int j = 0; j < C1; ++j) acc[j] += xv * W[i*C1+j];
        }
    }
    float dk = 0.f, dq = 0.f;
#pragma unroll
    for (int j = 0; j < C1; ++j) { dk += acc[j]*KV[j]; dq += acc[j]*QV[j]; }
    __half* o = xs1h + ((size_t)node * C1) * 2 + b;
#pragma unroll
    for (int j = 0; j < C1; ++j) o[2*j] = __float2half_rn(acc[j]);
    dotk1[node*2 + b] = dk; dotq1[node*2 + b] = dq;
}

// ---------------- per-edge attention precompute ------------------------------
// prec[e] = { src | p0h<<16,  p1h | efh<<16 }; p_b = sigmoid(dk[dst]+dq[src]+eb)
__global__ __launch_bounds__(256) void k_prep(
        const uint2* __restrict__ recs2seg, const float* __restrict__ dotk,
        const float* __restrict__ dotq, const float* __restrict__ ab,
        const float* __restrict__ sc, int scIdx, uint2* __restrict__ prec) {
    int e = blockIdx.x * 256 + threadIdx.x;      // grid exact: EE threads
    uint2 r = recs2seg[e];
    int src = r.x & 0xffff, dst = r.x >> 16;
    float ef = __uint_as_float(r.y);
    float eb = ef * sc[scIdx] + ab[0];
    float2 dk = *(const float2*)(dotk + dst*2);
    float2 dq = *(const float2*)(dotq + src*2);
    float p0 = sigmoidf(dk.x + dq.x + eb);
    float p1 = sigmoidf(dk.y + dq.y + eb);
    unsigned pu = __builtin_bit_cast(unsigned, __floats2half2_rn(p0, p1));
    unsigned eu = (unsigned)__half_as_ushort(__float2half_rn(ef));
    prec[e] = make_uint2((unsigned)src | (pu << 16),       // p0 in hi16 of x
                         (pu >> 16) | (eu << 16));         // p1 lo, ef hi
}

// ---------------- layer-1 fused gather+reduce: per-(node,cp), pipelined ------
__global__ __launch_bounds__(256) void k_aggr1f(
        const uint2* __restrict__ prec, const float* __restrict__ we,
        const uint2* __restrict__ xsh,
        const unsigned* __restrict__ startA, const unsigned* __restrict__ degA,
        float* __restrict__ aggrf) {
    int t = blockIdx.x * 256 + threadIdx.x;
    int node = t >> 3, cp = t & 7;
    if (node >= NN) return;
    unsigned s = startA[node];                   // absolute into prec
    unsigned n = degA[node];
    float w0 = we[2*cp], w1 = we[2*cp+1];
    float a0 = 0.f, a1 = 0.f, a2 = 0.f, a3 = 0.f;
    uint2 r_n = make_uint2(0u, 0u); uint2 xr_n = make_uint2(0u, 0u);
    if (n > 0) {
        r_n = prec[s];
        xr_n = xsh[(size_t)(r_n.x & 0xffff)*8 + cp];
    }
    for (unsigned i = 0; i < n; ++i) {
        uint2 r = r_n; uint2 xr = xr_n;
        if (i + 1 < n) {
            r_n = prec[s + i + 1];
            xr_n = xsh[(size_t)(r_n.x & 0xffff)*8 + cp];
        }
        float p0 = __half2float(__ushort_as_half((unsigned short)(r.x >> 16)));
        float p1 = __half2float(__ushort_as_half((unsigned short)(r.y & 0xffff)));
        float ef = __half2float(__ushort_as_half((unsigned short)(r.y >> 16)));
        float se0 = sigmoidf(ef * w0);
        float se1 = sigmoidf(ef * w1);
        float2 f0 = __half22float2(__builtin_bit_cast(__half2, xr.x));
        float2 f1 = __half22float2(__builtin_bit_cast(__half2, xr.y));
        a0 += p0 * se0 * f0.x;
        a1 += p1 * se0 * f0.y;
        a2 += p0 * se1 * f1.x;
        a3 += p1 * se1 * f1.y;
    }
    ((float4*)aggrf)[(size_t)node*8 + cp] = make_float4(a0, a1, a2, a3);
}

// ---------------- fused: update1 + leaky_relu + xs2 = X1 @ value2 ------------
__global__ __launch_bounds__(256) void k_update1(
        const float* __restrict__ cat_w, const float* __restrict__ cat_b,
        const float* __restrict__ value2,
        const float* __restrict__ key2, const float* __restrict__ query2,
        const float* __restrict__ aw2,
        const __half* __restrict__ xs1h, const float* __restrict__ aggr1f,
        __half* __restrict__ xs2h, float* __restrict__ dotk2, float* __restrict__ dotq2) {
    __shared__ float CW[2*C1*C1];
    __shared__ float CB[C1];
    __shared__ float V2[C1*C2];
    __shared__ float KV[C2], QV[C2];
    int tid = threadIdx.x;
    for (int i = tid; i < 2*C1*C1; i += 256) CW[i] = cat_w[i];
    for (int i = tid; i < C1*C2;   i += 256) V2[i] = value2[i];
    if (tid < C1) CB[tid] = cat_b[tid];
    if (tid < C2) {
        float kv = 0.f;
#pragma unroll
        for (int j = 0; j < C2; ++j) kv += key2[tid*C2+j] * aw2[j];
        KV[tid] = kv;
    } else if (tid < 2*C2) {
        int c = tid - C2;
        float qv = 0.f;
#pragma unroll
        for (int j = 0; j < C2; ++j) qv += query2[c*C2+j] * aw2[C2+j];
        QV[c] = qv;
    }
    __syncthreads();
    int bn = blockIdx.x * 256 + tid;
    if (bn >= NB) return;
    int b = (bn >= NN) ? 1 : 0;
    int node = bn - b*NN;
    const __half* xr = xs1h + ((size_t)node*C1)*2 + b;
    const float* agp = aggr1f + (size_t)node*32;
    float xd[C1], ag[C1];
#pragma unroll
    for (int i = 0; i < C1; ++i) xd[i] = __half2float(xr[2*i]);
#pragma unroll
    for (int i = 0; i < C1; ++i) ag[i] = agp[(i>>1)*4 + (i&1)*2 + b];
    float x1[C1];
#pragma unroll
    for (int j = 0; j < C1; ++j) {
        float u = CB[j];
#pragma unroll
        for (int i = 0; i < C1; ++i) {
            u += xd[i] * CW[i*C1 + j];
            u += ag[i] * CW[(C1+i)*C1 + j];
        }
        float o = xd[j] + fmaxf(u, 0.f);
        x1[j] = (o > 0.f) ? o : 0.01f * o;       // leaky_relu
    }
    float o2[C2];
#pragma unroll
    for (int k = 0; k < C2; ++k) o2[k] = 0.f;
#pragma unroll
    for (int j = 0; j < C1; ++j) {
        float xv = x1[j];
#pragma unroll
        for (int k = 0; k < C2; ++k) o2[k] += xv * V2[j*C2 + k];
    }
    float dk = 0.f, dq = 0.f;
#pragma unroll
    for (int k = 0; k < C2; ++k) { dk += o2[k]*KV[k]; dq += o2[k]*QV[k]; }
    __half* o = xs2h + ((size_t)node*C2)*2 + b;
#pragma unroll
    for (int k = 0; k < C2; ++k) o[2*k] = __float2half_rn(o2[k]);
    dotk2[node*2 + b] = dk; dotq2[node*2 + b] = dq;
}

// ---------------- layer-2 fused gather+reduce: per-(node,cp), pipelined ------
__global__ __launch_bounds__(256) void k_aggr2f(
        const uint2* __restrict__ prec, const float* __restrict__ we,
        const uint2* __restrict__ xsh,
        const unsigned* __restrict__ startA, const unsigned* __restrict__ degA,
        float* __restrict__ aggrf) {
    int t = blockIdx.x * 256 + threadIdx.x;
    int node = t >> 4, cp = t & 15;
    if (node >= NN) return;
    unsigned s = startA[NN + node] - EE;         // prec indexed from layer-2 base
    unsigned n = degA[NN + node];
    float w0 = we[2*cp], w1 = we[2*cp+1];
    float a0 = 0.f, a1 = 0.f, a2 = 0.f, a3 = 0.f;
    uint2 r_n = make_uint2(0u, 0u); uint2 xr_n = make_uint2(0u, 0u);
    if (n > 0) {
        r_n = prec[s];
        xr_n = xsh[(size_t)(r_n.x & 0xffff)*16 + cp];
    }
    for (unsigned i = 0; i < n; ++i) {
        uint2 r = r_n; uint2 xr = xr_n;
        if (i + 1 < n) {
            r_n = prec[s + i + 1];
            xr_n = xsh[(size_t)(r_n.x & 0xffff)*16 + cp];
        }
        float p0 = __half2float(__ushort_as_half((unsigned short)(r.x >> 16)));
        float p1 = __half2float(__ushort_as_half((unsigned short)(r.y & 0xffff)));
        float ef = __half2float(__ushort_as_half((unsigned short)(r.y >> 16)));
        float se0 = sigmoidf(ef * w0);
        float se1 = sigmoidf(ef * w1);
        float2 f0 = __half22float2(__builtin_bit_cast(__half2, xr.x));
        float2 f1 = __half22float2(__builtin_bit_cast(__half2, xr.y));
        a0 += p0 * se0 * f0.x;
        a1 += p1 * se0 * f0.y;
        a2 += p0 * se1 * f1.x;
        a3 += p1 * se1 * f1.y;
    }
    ((float4*)aggrf)[(size_t)node*16 + cp] = make_float4(a0, a1, a2, a3);
}

// ---------------- final: update2 -> fp32 out [b][node][c] --------------------
__global__ __launch_bounds__(256) void k_update2(
        const float* __restrict__ cat_w, const float* __restrict__ cat_b,
        const __half* __restrict__ xs2h, const float* __restrict__ aggr2f,
        float* __restrict__ out) {
    __shared__ float CW[2*C2*C2];
    __shared__ float CB[C2];
    int tid = threadIdx.x;
    for (int i = tid; i < 2*C2*C2; i += 256) CW[i] = cat_w[i];
    if (tid < C2) CB[tid] = cat_b[tid];
    __syncthreads();
    int bn = blockIdx.x * 256 + tid;
    if (bn >= NB) return;
    int b = (bn >= NN) ? 1 : 0;
    int node = bn - b*NN;
    const __half* xr = xs2h + ((size_t)node*C2)*2 + b;
    const float* agp = aggr2f + (size_t)node*64;
    float xd[C2], ag[C2];
#pragma unroll
    for (int i = 0; i < C2; ++i) xd[i] = __half2float(xr[2*i]);
#pragma unroll
    for (int i = 0; i < C2; ++i) ag[i] = agp[(i>>1)*4 + (i&1)*2 + b];
    float o[C2];
#pragma unroll
    for (int k = 0; k < C2; ++k) {
        float u = CB[k];
#pragma unroll
        for (int i = 0; i < C2; ++i) {
            u += xd[i] * CW[i*C2 + k];
            u += ag[i] * CW[(C2+i)*C2 + k];
        }
        o[k] = xd[k] + fmaxf(u, 0.f);
    }
    float4* dst = (float4*)(out + (size_t)bn * C2);
#pragma unroll
    for (int v = 0; v < 8; ++v)
        dst[v] = make_float4(o[4*v], o[4*v+1], o[4*v+2], o[4*v+3]);
}

extern "C" void kernel_launch(void* const* d_in, const int* in_sizes, int n_in,
                              void* d_out, int out_size, void* d_ws, size_t ws_size,
                              hipStream_t stream) {
    const float* X      = (const float*)d_in[0];
    const int*   ei0    = (const int*)d_in[1];
    const int*   ei1    = (const int*)d_in[2];
    const float* ew0    = (const float*)d_in[3];
    const float* ew1    = (const float*)d_in[4];
    // d_in[5], d_in[6]: res_n_id0/1 == arange(N) -> identity gather, unused
    const float* value1 = (const float*)d_in[7];
    const float* key1   = (const float*)d_in[8];
    const float* query1 = (const float*)d_in[9];
    const float* we1    = (const float*)d_in[10];
    const float* aw1    = (const float*)d_in[11];
    const float* ab1    = (const float*)d_in[12];
    const float* cw1    = (const float*)d_in[13];
    const float* cb1    = (const float*)d_in[14];
    const float* value2 = (const float*)d_in[15];
    const float* key2   = (const float*)d_in[16];
    const float* query2 = (const float*)d_in[17];
    const float* we2    = (const float*)d_in[18];
    const float* aw2    = (const float*)d_in[19];
    const float* ab2    = (const float*)d_in[20];
    const float* cw2    = (const float*)d_in[21];
    const float* cb2    = (const float*)d_in[22];
    float* ws  = (float*)d_ws;
    float* out = (float*)d_out;

    __half* xs1h = (__half*)(ws + OFF_XS1);
    __half* xs2h = (__half*)(ws + OFF_XS2);
    float* aggr1f = ws + OFF_AG1;
    float* aggr2f = ws + OFF_AG2;
    unsigned* blockCnt   = (unsigned*)(ws + OFF_BCNT);
    unsigned* bktTot     = (unsigned*)(ws + OFF_BTOT);
    unsigned* bucketBase = (unsigned*)(ws + OFF_BBASE);
    unsigned* startA     = (unsigned*)(ws + OFF_START);
    unsigned* degA       = (unsigned*)(ws + OFF_DEG);
    uint2*    recs2      = (uint2*)(ws + OFF_RECS2);
    uint2*    recs       = (uint2*)(ws + OFF_RECS);
    uint2*    prec       = (uint2*)(ws + OFF_PREC);    // overlays recs (dead)

    k_sc<<<1, 64, 0, stream>>>(we1, aw1, we2, aw2, ws + OFF_SC);

    // node transform (independent of binning)
    k_value1<<<(NB+255)/256, 256, 0, stream>>>(X, value1, key1, query1, aw1,
                                               xs1h, ws + OFF_DOTK1, ws + OFF_DOTQ1);

    // deterministic two-level sort of both layers' edges by dst
    k_cnt<<<NEBLK, TPB, 0, stream>>>(ei0, ei1, blockCnt);
    k_scanBkt<<<NBKT, 512, 0, stream>>>(blockCnt, bktTot);
    k_scanTot<<<1, 1024, 0, stream>>>(bktTot, bucketBase);
    k_permute<<<NEBLK, TPB, 0, stream>>>(ei0, ei1, ew0, ew1,
                                         blockCnt, bucketBase, recs);
    k_sortb<<<NBKT, 256, 0, stream>>>(recs, bktTot, bucketBase,
                                      recs2, startA, degA);

    // layer 1: per-edge attention precompute, then fused gather+reduce
    k_prep<<<EE/256, 256, 0, stream>>>(recs2, ws + OFF_DOTK1, ws + OFF_DOTQ1,
                                       ab1, ws + OFF_SC, 0, prec);
    k_aggr1f<<<(NN*8+255)/256, 256, 0, stream>>>(prec, we1, (const uint2*)xs1h,
                                                 startA, degA, aggr1f);
    k_update1<<<(NB+255)/256, 256, 0, stream>>>(cw1, cb1, value2, key2, query2, aw2,
                                                xs1h, aggr1f,
                                                xs2h, ws + OFF_DOTK2, ws + OFF_DOTQ2);

    // layer 2: same structure
    k_prep<<<EE/256, 256, 0, stream>>>(recs2 + EE, ws + OFF_DOTK2, ws + OFF_DOTQ2,
                                       ab2, ws + OFF_SC, 1, prec);
    k_aggr2f<<<(NN*16+255)/256, 256, 0, stream>>>(prec, we2, (const uint2*)xs2h,
                                                  startA, degA, aggr2f);
    k_update2<<<(NB+255)/256, 256, 0, stream>>>(cw2, cb2, xs2h, aggr2f, out);
}